// Round 6
// baseline (160.925 us; speedup 1.0000x reference)
//
#include <hip/hip_runtime.h>
#include <hip/hip_bf16.h>

typedef __attribute__((ext_vector_type(8))) short bf16x8;
typedef __attribute__((ext_vector_type(4))) float f32x4;

#define BB 4
#define TT 16
#define NT0 12
#define LL 64
#define CC 512
#define HH 8
#define HD 64
#define NQ (NT0*LL)       // 768 queries per batch
#define NCTX (TT*LL)      // 1024 cross keys per batch

#define GPTR(x) ((__attribute__((address_space(1))) void*)(x))
#define SPTR(x) ((__attribute__((address_space(3))) void*)(x))

__device__ __forceinline__ float bf2f(ushort u) {
  union { unsigned int i; float f; } x; x.i = ((unsigned int)u) << 16; return x.f;
}
__device__ __forceinline__ ushort f2bf(float f) {
  union { float f; unsigned int i; } x; x.f = f;
  unsigned int r = x.i + 0x7fffu + ((x.i >> 16) & 1u);  // RNE
  return (ushort)(r >> 16);
}

// Convert f32 inputs -> bf16 workspace, layout [qkv_w|k_w|v_w|proj_w|x|x_ctx|dx_ctx]
__global__ __launch_bounds__(256) void cvt_all(const float* __restrict__ w0,
                                               const float* __restrict__ w1,
                                               const float* __restrict__ w2,
                                               const float* __restrict__ w3,
                                               const float* __restrict__ x,
                                               const float* __restrict__ xc,
                                               const float* __restrict__ dxc,
                                               ushort* __restrict__ dst) {
  long i = (long)blockIdx.x * 256 + threadIdx.x;  // float4 index, total 1835008
  const float* src; long off;
  if (i < 196608)       { src = w0;  off = 0; }
  else if (i < 262144)  { src = w1;  off = 196608; }
  else if (i < 327680)  { src = w2;  off = 262144; }
  else if (i < 393216)  { src = w3;  off = 327680; }
  else if (i < 786432)  { src = x;   off = 393216; }
  else if (i < 1310720) { src = xc;  off = 786432; }
  else                  { src = dxc; off = 1310720; }
  f32x4 v = *(const f32x4*)(src + (i - off) * 4);
  ushort4 o = { f2bf(v[0]), f2bf(v[1]), f2bf(v[2]), f2bf(v[3]) };
  *(ushort4*)(dst + i * 4) = o;
}

// ---------------------------------------------------------------------------
// 128x128-tile GEMM block body, BK=64 (8 barrier iterations). K=512 fixed.
// C[m,n] = sum_k A[m,k]*W[n,k]. 4 waves in 2x2; wave = 64x64 (16 f32x4 acc).
// LDS: A-tile 128x64 + W-tile 128x64 (16 KB each), staged via global_load_lds
// width 16 (lane-contiguous dest). Chunk swizzle: chunk (row r, c) stored at
// slot c ^ (r&7); a row = 8 chunks = all 32 banks, so fragment ds_read_b128
// (16 rows x fixed chunk) hits each slot exactly 2x per kg -> conflict-free.
// ---------------------------------------------------------------------------
__device__ __forceinline__ void gemm128_mac(const ushort* __restrict__ A,
                                            const ushort* __restrict__ W,
                                            int mt, int nt, ushort* lds,
                                            f32x4* acc) {
  int t = threadIdx.x;
  ushort* ldsA = lds;          // 8192 ushorts
  ushort* ldsW = lds + 8192;

  const ushort *gA[4], *gW[4];
  ushort *lA[4], *lW[4];
#pragma unroll
  for (int i = 0; i < 4; ++i) {
    int p = t + 256 * i;       // chunk position 0..1023
    int r = p >> 3, cs = p & 7, c = cs ^ (r & 7);
    gA[i] = A + (size_t)(mt * 128 + r) * 512 + c * 8;
    gW[i] = W + (size_t)(nt * 128 + r) * 512 + c * 8;
    lA[i] = ldsA + p * 8;
    lW[i] = ldsW + p * 8;
  }

  int lane = t & 63, l15 = lane & 15, kg = lane >> 4;
  int wv = t >> 6;
  int mh = (wv >> 1) * 64, nh = (wv & 1) * 64;
  int slot0 = kg ^ (l15 & 7);
  const ushort* fa0 = ldsA + (mh + l15) * 64 + slot0 * 8;
  const ushort* fa1 = ldsA + (mh + l15) * 64 + (slot0 ^ 4) * 8;
  const ushort* fw0 = ldsW + (nh + l15) * 64 + slot0 * 8;
  const ushort* fw1 = ldsW + (nh + l15) * 64 + (slot0 ^ 4) * 8;

  for (int ks = 0; ks < 8; ++ks) {
    int ko = ks * 64;
#pragma unroll
    for (int i = 0; i < 4; ++i) {
      __builtin_amdgcn_global_load_lds(GPTR(gA[i] + ko), SPTR(lA[i]), 16, 0, 0);
      __builtin_amdgcn_global_load_lds(GPTR(gW[i] + ko), SPTR(lW[i]), 16, 0, 0);
    }
    __syncthreads();
    bf16x8 af[2][4], wf[2][4];
#pragma unroll
    for (int i = 0; i < 4; ++i) {
      af[0][i] = *(const bf16x8*)(fa0 + i * 1024);
      af[1][i] = *(const bf16x8*)(fa1 + i * 1024);
      wf[0][i] = *(const bf16x8*)(fw0 + i * 1024);
      wf[1][i] = *(const bf16x8*)(fw1 + i * 1024);
    }
#pragma unroll
    for (int h = 0; h < 2; ++h)
#pragma unroll
      for (int mi = 0; mi < 4; ++mi)
#pragma unroll
        for (int ni = 0; ni < 4; ++ni)
          acc[mi * 4 + ni] = __builtin_amdgcn_mfma_f32_16x16x32_bf16(
              af[h][mi], wf[h][ni], acc[mi * 4 + ni], 0, 0, 0);
    __syncthreads();
  }
}

// OUTMODE 0: C bf16 row-major [*,N]. 1: CT bf16 transposed CT[col*TM+row]
// (CT may be pre-offset). 2: Cf f32 row-major + bias.
template<int OUTMODE>
__device__ __forceinline__ void gemm128(const ushort* __restrict__ A,
                                        const ushort* __restrict__ W,
                                        ushort* __restrict__ C,
                                        ushort* __restrict__ CT,
                                        float* __restrict__ Cf,
                                        const float* __restrict__ bias,
                                        int mt, int nt, int N, long TM,
                                        ushort* lds) {
  f32x4 acc[16] = {{0,0,0,0},{0,0,0,0},{0,0,0,0},{0,0,0,0},
                   {0,0,0,0},{0,0,0,0},{0,0,0,0},{0,0,0,0},
                   {0,0,0,0},{0,0,0,0},{0,0,0,0},{0,0,0,0},
                   {0,0,0,0},{0,0,0,0},{0,0,0,0},{0,0,0,0}};
  gemm128_mac(A, W, mt, nt, lds, acc);

  int lane = threadIdx.x & 63, l15 = lane & 15, kg = lane >> 4;
  int wv = threadIdx.x >> 6;
  int Rw = mt * 128 + (wv >> 1) * 64;
  int Cw = nt * 128 + (wv & 1) * 64;
#pragma unroll
  for (int mi = 0; mi < 4; ++mi) {
    int row = Rw + mi * 16 + kg * 4;
#pragma unroll
    for (int ni = 0; ni < 4; ++ni) {
      f32x4 v = acc[mi * 4 + ni];
      int col = Cw + ni * 16 + l15;
      if (OUTMODE == 0) {
#pragma unroll
        for (int r = 0; r < 4; ++r) C[(size_t)(row + r) * N + col] = f2bf(v[r]);
      } else if (OUTMODE == 1) {
        ushort4 o = { f2bf(v[0]), f2bf(v[1]), f2bf(v[2]), f2bf(v[3]) };
        *(ushort4*)(CT + (long)col * TM + row) = o;
      } else {
        float bv = bias[col];
#pragma unroll
        for (int r = 0; r < 4; ++r) Cf[(size_t)(row + r) * N + col] = v[r] + bv;
      }
    }
  }
}

// Fused input GEMMs. blocks [0,288): qkv = x@qkv_w.T (24m x 12n tiles;
// n-tiles >=8 are self-V cols -> transposed into vselfT).
// [288,416): kctx = dx_ctx@k_w.T (32x4). [416,544): vctx^T (32x4).
__global__ __launch_bounds__(256) void gemm3(const ushort* __restrict__ xb,
                                             const ushort* __restrict__ dxb,
                                             const ushort* __restrict__ xcb,
                                             const ushort* __restrict__ qkvwb,
                                             const ushort* __restrict__ kwb,
                                             const ushort* __restrict__ vwb,
                                             ushort* __restrict__ qkv,
                                             ushort* __restrict__ vselfT,
                                             ushort* __restrict__ kctx,
                                             ushort* __restrict__ vctxT) {
  __shared__ ushort lds[16384];
  int blk = blockIdx.x;
  if (blk < 288) {
    int mt = blk % 24, nt = blk / 24;
    if (nt < 8)
      gemm128<0>(xb, qkvwb, qkv, nullptr, nullptr, nullptr, mt, nt, 1536, 0, lds);
    else
      gemm128<1>(xb, qkvwb, nullptr, vselfT - (size_t)1024 * 3072, nullptr, nullptr,
                 mt, nt, 1536, 3072, lds);
  } else if (blk < 416) {
    int r = blk - 288;
    gemm128<0>(dxb, kwb, kctx, nullptr, nullptr, nullptr, r % 32, r / 32, 512, 0, lds);
  } else {
    int r = blk - 416;
    gemm128<1>(xcb, vwb, nullptr, vctxT, nullptr, nullptr, r % 32, r / 32, 512, 4096, lds);
  }
}

__global__ __launch_bounds__(256) void gemm_proj(const ushort* __restrict__ aout,
                                                 const ushort* __restrict__ pwb,
                                                 const float* __restrict__ bias,
                                                 float* __restrict__ out) {
  __shared__ ushort lds[16384];
  int blk = blockIdx.x;  // 96 blocks: 24 mt x 4 nt
  gemm128<2>(aout, pwb, nullptr, nullptr, out, bias, blk % 24, blk / 24, 512, 0, lds);
}

// Flash attention, S^T orientation, split-K. Block = (b, h, frame t0);
// 8 waves = 4 q-groups x 2 key-sides. Side 0: tiles 0..7 + self; side 1:
// tiles 8..15. LSE merge through LDS (reuses Pt strips after barrier).
__global__ __launch_bounds__(512) void flash_attn(const ushort* __restrict__ qkv,
                                                  const ushort* __restrict__ kctx,
                                                  const ushort* __restrict__ vctxT,
                                                  const ushort* __restrict__ vselfT,
                                                  const int* __restrict__ ctx_mask,
                                                  ushort* __restrict__ aout) {
  __shared__ ushort Pt[8][1152];     // per-wave P^T strip (16 x 64, stride 72)
  int blk = blockIdx.x;              // b*96 + h*12 + t0
  int t0 = blk % NT0;
  int h  = (blk / NT0) % HH;
  int b  = blk / (NT0 * HH);
  int tid = threadIdx.x, wv = tid >> 6, lane = tid & 63;
  int qg = wv & 3, kside = wv >> 2;
  int l15 = lane & 15, kg = lane >> 4;

  int qrow = b * NQ + t0 * LL + qg * 16 + l15;
  const ushort* qp = qkv + (size_t)qrow * 1536 + h * HD + kg * 8;
  bf16x8 q0 = *(const bf16x8*)qp;
  bf16x8 q1 = *(const bf16x8*)(qp + 32);

  f32x4 acc[4] = {{0,0,0,0},{0,0,0,0},{0,0,0,0},{0,0,0,0}};
  float Mr = -INFINITY, Lr = 0.f;
  ushort* myPt = &Pt[wv][0];

  int nkt = kside ? 8 : 9;
  for (int ki = 0; ki < nkt; ++ki) {
    bool self = (!kside) && (ki == 8);
    int kt = kside ? (8 + ki) : ki;  // cross-tile index when !self
    const ushort* kbase; int kstr;
    if (!self) {
      if (!(ctx_mask[b * TT + kt] != 0 && kt != t0 + 4)) continue;
      kbase = kctx + (size_t)(b * NCTX + kt * LL) * CC + h * HD;
      kstr = CC;
    } else {
      kbase = qkv + (size_t)(b * NQ + t0 * LL) * 1536 + CC + h * HD;
      kstr = 1536;
    }

    // S^T tile: 64 keys x 16 q (A = K rows, B = Q)
    f32x4 s[4];
#pragma unroll
    for (int st = 0; st < 4; ++st) {
      const ushort* kp = kbase + (size_t)(st * 16 + l15) * kstr + kg * 8;
      bf16x8 k0 = *(const bf16x8*)kp;
      bf16x8 k1 = *(const bf16x8*)(kp + 32);
      f32x4 z = {0, 0, 0, 0};
      z = __builtin_amdgcn_mfma_f32_16x16x32_bf16(k0, q0, z, 0, 0, 0);
      z = __builtin_amdgcn_mfma_f32_16x16x32_bf16(k1, q1, z, 0, 0, 0);
      s[st] = z * 0.125f;
    }

    float tmax = -INFINITY;
#pragma unroll
    for (int st = 0; st < 4; ++st)
#pragma unroll
      for (int r = 0; r < 4; ++r) tmax = fmaxf(tmax, s[st][r]);
    tmax = fmaxf(tmax, __shfl_xor(tmax, 16, 64));
    tmax = fmaxf(tmax, __shfl_xor(tmax, 32, 64));
    float Mn = fmaxf(Mr, tmax);
    float alpha = __expf(Mr - Mn);
    Mr = Mn;
    float tsum = 0.f;
#pragma unroll
    for (int st = 0; st < 4; ++st)
#pragma unroll
      for (int r = 0; r < 4; ++r) {
        float p = __expf(s[st][r] - Mr);
        s[st][r] = p;
        tsum += p;
      }
    tsum += __shfl_xor(tsum, 16, 64);
    tsum += __shfl_xor(tsum, 32, 64);
    Lr = Lr * alpha + tsum;
#pragma unroll
    for (int d = 0; d < 4; ++d) acc[d] *= alpha;

#pragma unroll
    for (int st = 0; st < 4; ++st) {
      ushort4 pk = { f2bf(s[st][0]), f2bf(s[st][1]), f2bf(s[st][2]), f2bf(s[st][3]) };
      *(ushort4*)(myPt + l15 * 72 + st * 16 + kg * 4) = pk;
    }

    const ushort* vtb; int vtN;
    if (!self) { vtb = vctxT + (size_t)h * HD * (BB * NCTX) + b * NCTX + kt * LL; vtN = BB * NCTX; }
    else       { vtb = vselfT + (size_t)h * HD * (BB * NQ) + b * NQ + t0 * LL;   vtN = BB * NQ; }
#pragma unroll
    for (int kc = 0; kc < 2; ++kc) {
      bf16x8 pb = *(const bf16x8*)(myPt + l15 * 72 + kc * 32 + kg * 8);
#pragma unroll
      for (int d = 0; d < 4; ++d) {
        const ushort* vp = vtb + (size_t)(d * 16 + l15) * vtN + kc * 32 + kg * 8;
        bf16x8 vf = *(const bf16x8*)vp;
        acc[d] = __builtin_amdgcn_mfma_f32_16x16x32_bf16(vf, pb, acc[d], 0, 0, 0);
      }
    }
  }

  // ---- LSE merge: side 1 publishes state, side 0 merges & writes ----
  __syncthreads();
  float* base = (float*)&Pt[0][0] + (size_t)qg * 1152;  // 1024 acc + 64 M + 64 L
  if (kside) {
#pragma unroll
    for (int d = 0; d < 4; ++d) *(f32x4*)(base + lane * 16 + d * 4) = acc[d];
    base[1024 + lane] = Mr;
    base[1088 + lane] = Lr;
  }
  __syncthreads();
  if (!kside) {
    float M1 = base[1024 + lane], L1 = base[1088 + lane];
    float Mn = fmaxf(Mr, M1);           // Mr finite (self tile always valid)
    float a0 = __expf(Mr - Mn), a1 = __expf(M1 - Mn);
    float inv = 1.f / (Lr * a0 + L1 * a1);
    int orow = b * NQ + t0 * LL + qg * 16 + l15;
#pragma unroll
    for (int d = 0; d < 4; ++d) {
      f32x4 o1 = *(const f32x4*)(base + lane * 16 + d * 4);
      f32x4 v = acc[d] * a0 + o1 * a1;
      ushort4 o = { f2bf(v[0] * inv), f2bf(v[1] * inv),
                    f2bf(v[2] * inv), f2bf(v[3] * inv) };
      *(ushort4*)(aout + (size_t)orow * CC + h * HD + d * 16 + kg * 4) = o;
    }
  }
}

extern "C" void kernel_launch(void* const* d_in, const int* in_sizes, int n_in,
                              void* d_out, int out_size, void* d_ws, size_t ws_size,
                              hipStream_t stream) {
  const float* x        = (const float*)d_in[0];
  const float* x_ctx    = (const float*)d_in[1];
  const float* dx_ctx   = (const float*)d_in[2];
  const int*   ctx_mask = (const int*)d_in[3];
  const float* qkv_w    = (const float*)d_in[4];
  const float* k_w      = (const float*)d_in[5];
  const float* v_w      = (const float*)d_in[6];
  const float* proj_w   = (const float*)d_in[7];
  const float* proj_b   = (const float*)d_in[8];
  float* out = (float*)d_out;

  ushort* ws = (ushort*)d_ws;   // element offsets (bf16)
  ushort* qkvwb  = ws;                    //  786432
  ushort* kwb    = ws + 786432;           //  262144
  ushort* vwb    = ws + 1048576;          //  262144
  ushort* pwb    = ws + 1310720;          //  262144
  ushort* xb     = ws + 1572864;          // 1572864  (3072x512)
  ushort* xcb    = ws + 3145728;          // 2097152  (4096x512)
  ushort* dxb    = ws + 5242880;          // 2097152  (4096x512)
  ushort* qkv    = ws + 7340032;          // 3072x1536
  ushort* kctx   = ws + 12058624;         // 4096x512
  ushort* vctxT  = ws + 14155776;         // 512x4096
  ushort* vselfT = ws + 16252928;         // 512x3072
  ushort* aout   = ws + 17825792;         // 3072x512  (end 19398656 el = 38.8MB)

  cvt_all<<<7168, 256, 0, stream>>>(qkv_w, k_w, v_w, proj_w, x, x_ctx, dx_ctx, ws);
  gemm3<<<544, 256, 0, stream>>>(xb, dxb, xcb, qkvwb, kwb, vwb,
                                 qkv, vselfT, kctx, vctxT);
  flash_attn<<<BB * HH * NT0, 512, 0, stream>>>(qkv, kctx, vctxT, vselfT, ctx_mask, aout);
  gemm_proj<<<96, 256, 0, stream>>>(aout, pwb, proj_b, out);
}

// Round 7
// 151.357 us; speedup vs baseline: 1.0632x; 1.0632x over previous
//
#include <hip/hip_runtime.h>
#include <hip/hip_bf16.h>

typedef __attribute__((ext_vector_type(8))) short bf16x8;
typedef __attribute__((ext_vector_type(4))) float f32x4;

#define BB 4
#define TT 16
#define NT0 12
#define LL 64
#define CC 512
#define HH 8
#define HD 64
#define NQ (NT0*LL)       // 768 queries per batch
#define NCTX (TT*LL)      // 1024 cross keys per batch

#define GPTR(x) ((__attribute__((address_space(1))) void*)(x))
#define SPTR(x) ((__attribute__((address_space(3))) void*)(x))

__device__ __forceinline__ float bf2f(ushort u) {
  union { unsigned int i; float f; } x; x.i = ((unsigned int)u) << 16; return x.f;
}
__device__ __forceinline__ ushort f2bf(float f) {
  union { float f; unsigned int i; } x; x.f = f;
  unsigned int r = x.i + 0x7fffu + ((x.i >> 16) & 1u);  // RNE
  return (ushort)(r >> 16);
}

// Convert f32 inputs -> bf16 workspace, layout [qkv_w|k_w|v_w|proj_w|x|x_ctx|dx_ctx]
__global__ __launch_bounds__(256) void cvt_all(const float* __restrict__ w0,
                                               const float* __restrict__ w1,
                                               const float* __restrict__ w2,
                                               const float* __restrict__ w3,
                                               const float* __restrict__ x,
                                               const float* __restrict__ xc,
                                               const float* __restrict__ dxc,
                                               ushort* __restrict__ dst) {
  long i = (long)blockIdx.x * 256 + threadIdx.x;  // float4 index, total 1835008
  const float* src; long off;
  if (i < 196608)       { src = w0;  off = 0; }
  else if (i < 262144)  { src = w1;  off = 196608; }
  else if (i < 327680)  { src = w2;  off = 262144; }
  else if (i < 393216)  { src = w3;  off = 327680; }
  else if (i < 786432)  { src = x;   off = 393216; }
  else if (i < 1310720) { src = xc;  off = 786432; }
  else                  { src = dxc; off = 1310720; }
  f32x4 v = *(const f32x4*)(src + (i - off) * 4);
  ushort4 o = { f2bf(v[0]), f2bf(v[1]), f2bf(v[2]), f2bf(v[3]) };
  *(ushort4*)(dst + i * 4) = o;
}

// ---------------------------------------------------------------------------
// 128x128-tile GEMM block body (R5-proven, BK=32). K=512 fixed, stride 512.
// 4 waves in 2x2; wave = 64x64 (16 f32x4 acc). LDS: A/W tiles 128x32 (8KB ea),
// staged with global_load_lds width 16. XOR chunk swizzle keeps ds_read_b128
// fragment reads 2-way-per-bank (free, m136).
// ---------------------------------------------------------------------------
__device__ __forceinline__ void gemm128_mac(const ushort* __restrict__ A,
                                            const ushort* __restrict__ W,
                                            int mt, int nt, ushort* lds,
                                            f32x4* acc) {
  int t = threadIdx.x;
  ushort* ldsA = lds;
  ushort* ldsW = lds + 4096;

  int p0 = t, p1 = t + 256;
  int r0 = p0 >> 2, r1 = p1 >> 2;
  int c0 = (p0 & 3) ^ ((r0 >> 1) & 3);
  int c1 = (p1 & 3) ^ ((r1 >> 1) & 3);
  const ushort* ga0 = A + (size_t)(mt * 128 + r0) * 512 + c0 * 8;
  const ushort* ga1 = A + (size_t)(mt * 128 + r1) * 512 + c1 * 8;
  const ushort* gw0 = W + (size_t)(nt * 128 + r0) * 512 + c0 * 8;
  const ushort* gw1 = W + (size_t)(nt * 128 + r1) * 512 + c1 * 8;
  ushort* la0 = ldsA + p0 * 8;
  ushort* la1 = ldsA + p1 * 8;
  ushort* lw0 = ldsW + p0 * 8;
  ushort* lw1 = ldsW + p1 * 8;

  int lane = t & 63, l15 = lane & 15, kg = lane >> 4;
  int wv = t >> 6;
  int mh = (wv >> 1) * 64, nh = (wv & 1) * 64;
  int swz = kg ^ ((l15 >> 1) & 3);
  const ushort* fa = ldsA + (mh + l15) * 32 + swz * 8;
  const ushort* fw = ldsW + (nh + l15) * 32 + swz * 8;

  for (int ks = 0; ks < 16; ++ks) {
    int ko = ks * 32;
    __builtin_amdgcn_global_load_lds(GPTR(ga0 + ko), SPTR(la0), 16, 0, 0);
    __builtin_amdgcn_global_load_lds(GPTR(ga1 + ko), SPTR(la1), 16, 0, 0);
    __builtin_amdgcn_global_load_lds(GPTR(gw0 + ko), SPTR(lw0), 16, 0, 0);
    __builtin_amdgcn_global_load_lds(GPTR(gw1 + ko), SPTR(lw1), 16, 0, 0);
    __syncthreads();
    bf16x8 af[4], wf[4];
#pragma unroll
    for (int i = 0; i < 4; ++i) af[i] = *(const bf16x8*)(fa + i * 512);
#pragma unroll
    for (int i = 0; i < 4; ++i) wf[i] = *(const bf16x8*)(fw + i * 512);
#pragma unroll
    for (int mi = 0; mi < 4; ++mi)
#pragma unroll
      for (int ni = 0; ni < 4; ++ni)
        acc[mi * 4 + ni] =
            __builtin_amdgcn_mfma_f32_16x16x32_bf16(af[mi], wf[ni], acc[mi * 4 + ni], 0, 0, 0);
    __syncthreads();
  }
}

// OUTMODE 0: C bf16 row-major [*,N]. 1: CT bf16 transposed CT[col*TM+row]
// (CT may be pre-offset). 2: Cf f32 row-major + bias.
template<int OUTMODE>
__device__ __forceinline__ void gemm128(const ushort* __restrict__ A,
                                        const ushort* __restrict__ W,
                                        ushort* __restrict__ C,
                                        ushort* __restrict__ CT,
                                        float* __restrict__ Cf,
                                        const float* __restrict__ bias,
                                        int mt, int nt, int N, long TM,
                                        ushort* lds) {
  f32x4 acc[16] = {{0,0,0,0},{0,0,0,0},{0,0,0,0},{0,0,0,0},
                   {0,0,0,0},{0,0,0,0},{0,0,0,0},{0,0,0,0},
                   {0,0,0,0},{0,0,0,0},{0,0,0,0},{0,0,0,0},
                   {0,0,0,0},{0,0,0,0},{0,0,0,0},{0,0,0,0}};
  gemm128_mac(A, W, mt, nt, lds, acc);

  int lane = threadIdx.x & 63, l15 = lane & 15, kg = lane >> 4;
  int wv = threadIdx.x >> 6;
  int Rw = mt * 128 + (wv >> 1) * 64;
  int Cw = nt * 128 + (wv & 1) * 64;
#pragma unroll
  for (int mi = 0; mi < 4; ++mi) {
    int row = Rw + mi * 16 + kg * 4;
#pragma unroll
    for (int ni = 0; ni < 4; ++ni) {
      f32x4 v = acc[mi * 4 + ni];
      int col = Cw + ni * 16 + l15;
      if (OUTMODE == 0) {
#pragma unroll
        for (int r = 0; r < 4; ++r) C[(size_t)(row + r) * N + col] = f2bf(v[r]);
      } else if (OUTMODE == 1) {
        ushort4 o = { f2bf(v[0]), f2bf(v[1]), f2bf(v[2]), f2bf(v[3]) };
        *(ushort4*)(CT + (long)col * TM + row) = o;
      } else {
        float bv = bias[col];
#pragma unroll
        for (int r = 0; r < 4; ++r) Cf[(size_t)(row + r) * N + col] = v[r] + bv;
      }
    }
  }
}

// Fused input GEMMs. blocks [0,288): qkv = x@qkv_w.T (24m x 12n tiles;
// n-tiles >=8 are self-V cols -> transposed into vselfT).
// [288,416): kctx = dx_ctx@k_w.T (32x4). [416,544): vctx^T (32x4).
__global__ __launch_bounds__(256) void gemm3(const ushort* __restrict__ xb,
                                             const ushort* __restrict__ dxb,
                                             const ushort* __restrict__ xcb,
                                             const ushort* __restrict__ qkvwb,
                                             const ushort* __restrict__ kwb,
                                             const ushort* __restrict__ vwb,
                                             ushort* __restrict__ qkv,
                                             ushort* __restrict__ vselfT,
                                             ushort* __restrict__ kctx,
                                             ushort* __restrict__ vctxT) {
  __shared__ ushort lds[8192];
  int blk = blockIdx.x;
  if (blk < 288) {
    int mt = blk % 24, nt = blk / 24;
    if (nt < 8)
      gemm128<0>(xb, qkvwb, qkv, nullptr, nullptr, nullptr, mt, nt, 1536, 0, lds);
    else
      gemm128<1>(xb, qkvwb, nullptr, vselfT - (size_t)1024 * 3072, nullptr, nullptr,
                 mt, nt, 1536, 3072, lds);
  } else if (blk < 416) {
    int r = blk - 288;
    gemm128<0>(dxb, kwb, kctx, nullptr, nullptr, nullptr, r % 32, r / 32, 512, 0, lds);
  } else {
    int r = blk - 416;
    gemm128<1>(xcb, vwb, nullptr, vctxT, nullptr, nullptr, r % 32, r / 32, 512, 4096, lds);
  }
}

__global__ __launch_bounds__(256) void gemm_proj(const ushort* __restrict__ aout,
                                                 const ushort* __restrict__ pwb,
                                                 const float* __restrict__ bias,
                                                 float* __restrict__ out) {
  __shared__ ushort lds[8192];
  int blk = blockIdx.x;  // 96 blocks: 24 mt x 4 nt
  gemm128<2>(aout, pwb, nullptr, nullptr, out, bias, blk % 24, blk / 24, 512, 0, lds);
}

// Flash attention, S^T orientation, 4-way split-K, half-frame blocks.
// Block = (b, h, t0, qh): 768 blocks x 512 threads = 2 q-groups x 4 key-splits.
// ks0: cross tiles 0-3 + self; ks1/2/3: tiles 4-7 / 8-11 / 12-15.
// 4-way LSE merge through LDS (merge regions alias the dead Pt strips).
__global__ __launch_bounds__(512) void flash_attn(const ushort* __restrict__ qkv,
                                                  const ushort* __restrict__ kctx,
                                                  const ushort* __restrict__ vctxT,
                                                  const ushort* __restrict__ vselfT,
                                                  const int* __restrict__ ctx_mask,
                                                  ushort* __restrict__ aout) {
  __shared__ float smem[6912];       // 27648 B: 6 merge regions of 1152 floats;
                                     // first 18432 B alias 8 Pt strips (1152 ushorts)
  int blk = blockIdx.x;              // ((b*8+h)*12+t0)*2 + qh
  int qh = blk & 1;
  int rest = blk >> 1;
  int t0 = rest % NT0;
  int h  = (rest / NT0) % HH;
  int b  = rest / (NT0 * HH);
  int tid = threadIdx.x, wv = tid >> 6, lane = tid & 63;
  int qg = wv & 1, ks = wv >> 1;     // ks in [0,4)
  int l15 = lane & 15, kg = lane >> 4;

  int qrow = b * NQ + t0 * LL + qh * 32 + qg * 16 + l15;
  const ushort* qp = qkv + (size_t)qrow * 1536 + h * HD + kg * 8;
  bf16x8 q0 = *(const bf16x8*)qp;
  bf16x8 q1 = *(const bf16x8*)(qp + 32);

  f32x4 acc[4] = {{0,0,0,0},{0,0,0,0},{0,0,0,0},{0,0,0,0}};
  float Mr = -INFINITY, Lr = 0.f;
  ushort* myPt = (ushort*)smem + wv * 1152;  // 16 x 64 strip, stride 72

  int nkt = (ks == 0) ? 5 : 4;
  for (int ki = 0; ki < nkt; ++ki) {
    bool self = (ks == 0) && (ki == 4);
    int kt = ks * 4 + ki;            // cross-tile index when !self
    const ushort* kbase; int kstr;
    if (!self) {
      if (!(ctx_mask[b * TT + kt] != 0 && kt != t0 + 4)) continue;
      kbase = kctx + (size_t)(b * NCTX + kt * LL) * CC + h * HD;
      kstr = CC;
    } else {
      kbase = qkv + (size_t)(b * NQ + t0 * LL) * 1536 + CC + h * HD;
      kstr = 1536;
    }

    // S^T tile: 64 keys x 16 q (A = K rows, B = Q)
    f32x4 s[4];
#pragma unroll
    for (int st = 0; st < 4; ++st) {
      const ushort* kp = kbase + (size_t)(st * 16 + l15) * kstr + kg * 8;
      bf16x8 k0 = *(const bf16x8*)kp;
      bf16x8 k1 = *(const bf16x8*)(kp + 32);
      f32x4 z = {0, 0, 0, 0};
      z = __builtin_amdgcn_mfma_f32_16x16x32_bf16(k0, q0, z, 0, 0, 0);
      z = __builtin_amdgcn_mfma_f32_16x16x32_bf16(k1, q1, z, 0, 0, 0);
      s[st] = z * 0.125f;
    }

    float tmax = -INFINITY;
#pragma unroll
    for (int st = 0; st < 4; ++st)
#pragma unroll
      for (int r = 0; r < 4; ++r) tmax = fmaxf(tmax, s[st][r]);
    tmax = fmaxf(tmax, __shfl_xor(tmax, 16, 64));
    tmax = fmaxf(tmax, __shfl_xor(tmax, 32, 64));
    float Mn = fmaxf(Mr, tmax);
    float alpha = __expf(Mr - Mn);
    Mr = Mn;
    float tsum = 0.f;
#pragma unroll
    for (int st = 0; st < 4; ++st)
#pragma unroll
      for (int r = 0; r < 4; ++r) {
        float p = __expf(s[st][r] - Mr);
        s[st][r] = p;
        tsum += p;
      }
    tsum += __shfl_xor(tsum, 16, 64);
    tsum += __shfl_xor(tsum, 32, 64);
    Lr = Lr * alpha + tsum;
#pragma unroll
    for (int d = 0; d < 4; ++d) acc[d] *= alpha;

#pragma unroll
    for (int st = 0; st < 4; ++st) {
      ushort4 pk = { f2bf(s[st][0]), f2bf(s[st][1]), f2bf(s[st][2]), f2bf(s[st][3]) };
      *(ushort4*)(myPt + l15 * 72 + st * 16 + kg * 4) = pk;
    }

    const ushort* vtb; int vtN;
    if (!self) { vtb = vctxT + (size_t)h * HD * (BB * NCTX) + b * NCTX + kt * LL; vtN = BB * NCTX; }
    else       { vtb = vselfT + (size_t)h * HD * (BB * NQ) + b * NQ + t0 * LL;   vtN = BB * NQ; }
#pragma unroll
    for (int kc = 0; kc < 2; ++kc) {
      bf16x8 pb = *(const bf16x8*)(myPt + l15 * 72 + kc * 32 + kg * 8);
#pragma unroll
      for (int d = 0; d < 4; ++d) {
        const ushort* vp = vtb + (size_t)(d * 16 + l15) * vtN + kc * 32 + kg * 8;
        bf16x8 vf = *(const bf16x8*)vp;
        acc[d] = __builtin_amdgcn_mfma_f32_16x16x32_bf16(vf, pb, acc[d], 0, 0, 0);
      }
    }
  }

  // ---- 4-way LSE merge: ks1..3 publish, ks0 merges & writes ----
  __syncthreads();
  if (ks) {
    float* reg = smem + (size_t)(qg * 3 + ks - 1) * 1152;  // 1024 acc + 64 M + 64 L
#pragma unroll
    for (int d = 0; d < 4; ++d) *(f32x4*)(reg + lane * 16 + d * 4) = acc[d];
    reg[1024 + lane] = Mr;
    reg[1088 + lane] = Lr;
  }
  __syncthreads();
  if (!ks) {
    float Mj[3], Lj[3];
    float Ms = Mr;                    // finite: self tile always valid
#pragma unroll
    for (int j = 0; j < 3; ++j) {
      const float* reg = smem + (size_t)(qg * 3 + j) * 1152;
      Mj[j] = reg[1024 + lane];
      Lj[j] = reg[1088 + lane];
      Ms = fmaxf(Ms, Mj[j]);
    }
    float a0 = __expf(Mr - Ms);
    float Ls = Lr * a0;
    f32x4 o[4];
#pragma unroll
    for (int d = 0; d < 4; ++d) o[d] = acc[d] * a0;
#pragma unroll
    for (int j = 0; j < 3; ++j) {
      const float* reg = smem + (size_t)(qg * 3 + j) * 1152;
      float aj = __expf(Mj[j] - Ms);
      Ls += Lj[j] * aj;
#pragma unroll
      for (int d = 0; d < 4; ++d)
        o[d] += *(const f32x4*)(reg + lane * 16 + d * 4) * aj;
    }
    float inv = 1.f / Ls;
    int orow = b * NQ + t0 * LL + qh * 32 + qg * 16 + l15;
#pragma unroll
    for (int d = 0; d < 4; ++d) {
      ushort4 ov = { f2bf(o[d][0] * inv), f2bf(o[d][1] * inv),
                     f2bf(o[d][2] * inv), f2bf(o[d][3] * inv) };
      *(ushort4*)(aout + (size_t)orow * CC + h * HD + d * 16 + kg * 4) = ov;
    }
  }
}

extern "C" void kernel_launch(void* const* d_in, const int* in_sizes, int n_in,
                              void* d_out, int out_size, void* d_ws, size_t ws_size,
                              hipStream_t stream) {
  const float* x        = (const float*)d_in[0];
  const float* x_ctx    = (const float*)d_in[1];
  const float* dx_ctx   = (const float*)d_in[2];
  const int*   ctx_mask = (const int*)d_in[3];
  const float* qkv_w    = (const float*)d_in[4];
  const float* k_w      = (const float*)d_in[5];
  const float* v_w      = (const float*)d_in[6];
  const float* proj_w   = (const float*)d_in[7];
  const float* proj_b   = (const float*)d_in[8];
  float* out = (float*)d_out;

  ushort* ws = (ushort*)d_ws;   // element offsets (bf16)
  ushort* qkvwb  = ws;                    //  786432
  ushort* kwb    = ws + 786432;           //  262144
  ushort* vwb    = ws + 1048576;          //  262144
  ushort* pwb    = ws + 1310720;          //  262144
  ushort* xb     = ws + 1572864;          // 1572864  (3072x512)
  ushort* xcb    = ws + 3145728;          // 2097152  (4096x512)
  ushort* dxb    = ws + 5242880;          // 2097152  (4096x512)
  ushort* qkv    = ws + 7340032;          // 3072x1536
  ushort* kctx   = ws + 12058624;         // 4096x512
  ushort* vctxT  = ws + 14155776;         // 512x4096
  ushort* vselfT = ws + 16252928;         // 512x3072
  ushort* aout   = ws + 17825792;         // 3072x512  (end 19398656 el = 38.8MB)

  cvt_all<<<7168, 256, 0, stream>>>(qkv_w, k_w, v_w, proj_w, x, x_ctx, dx_ctx, ws);
  gemm3<<<544, 256, 0, stream>>>(xb, dxb, xcb, qkvwb, kwb, vwb,
                                 qkv, vselfT, kctx, vctxT);
  flash_attn<<<768, 512, 0, stream>>>(qkv, kctx, vctxT, vselfT, ctx_mask, aout);
  gemm_proj<<<96, 256, 0, stream>>>(aout, pwb, proj_b, out);
}

// Round 8
// 149.820 us; speedup vs baseline: 1.0741x; 1.0103x over previous
//
#include <hip/hip_runtime.h>
#include <hip/hip_bf16.h>

typedef __attribute__((ext_vector_type(8))) short bf16x8;
typedef __attribute__((ext_vector_type(4))) float f32x4;

#define BB 4
#define TT 16
#define NT0 12
#define LL 64
#define CC 512
#define HH 8
#define HD 64
#define NQ (NT0*LL)       // 768 queries per batch
#define NCTX (TT*LL)      // 1024 cross keys per batch

#define GPTR(x) ((__attribute__((address_space(1))) void*)(x))
#define SPTR(x) ((__attribute__((address_space(3))) void*)(x))

__device__ __forceinline__ float bf2f(ushort u) {
  union { unsigned int i; float f; } x; x.i = ((unsigned int)u) << 16; return x.f;
}
__device__ __forceinline__ ushort f2bf(float f) {
  union { float f; unsigned int i; } x; x.f = f;
  unsigned int r = x.i + 0x7fffu + ((x.i >> 16) & 1u);  // RNE
  return (ushort)(r >> 16);
}

// Convert f32 inputs -> bf16 workspace, layout [qkv_w|k_w|v_w|proj_w|x|x_ctx|dx_ctx]
__global__ __launch_bounds__(256) void cvt_all(const float* __restrict__ w0,
                                               const float* __restrict__ w1,
                                               const float* __restrict__ w2,
                                               const float* __restrict__ w3,
                                               const float* __restrict__ x,
                                               const float* __restrict__ xc,
                                               const float* __restrict__ dxc,
                                               ushort* __restrict__ dst) {
  long i = (long)blockIdx.x * 256 + threadIdx.x;  // float4 index, total 1835008
  const float* src; long off;
  if (i < 196608)       { src = w0;  off = 0; }
  else if (i < 262144)  { src = w1;  off = 196608; }
  else if (i < 327680)  { src = w2;  off = 262144; }
  else if (i < 393216)  { src = w3;  off = 327680; }
  else if (i < 786432)  { src = x;   off = 393216; }
  else if (i < 1310720) { src = xc;  off = 786432; }
  else                  { src = dxc; off = 1310720; }
  f32x4 v = *(const f32x4*)(src + (i - off) * 4);
  ushort4 o = { f2bf(v[0]), f2bf(v[1]), f2bf(v[2]), f2bf(v[3]) };
  *(ushort4*)(dst + i * 4) = o;
}

// ---------------------------------------------------------------------------
// 128x128-tile GEMM block body (R5-proven, BK=32). K=512 fixed, stride 512.
// ---------------------------------------------------------------------------
__device__ __forceinline__ void gemm128_mac(const ushort* __restrict__ A,
                                            const ushort* __restrict__ W,
                                            int mt, int nt, ushort* lds,
                                            f32x4* acc) {
  int t = threadIdx.x;
  ushort* ldsA = lds;
  ushort* ldsW = lds + 4096;

  int p0 = t, p1 = t + 256;
  int r0 = p0 >> 2, r1 = p1 >> 2;
  int c0 = (p0 & 3) ^ ((r0 >> 1) & 3);
  int c1 = (p1 & 3) ^ ((r1 >> 1) & 3);
  const ushort* ga0 = A + (size_t)(mt * 128 + r0) * 512 + c0 * 8;
  const ushort* ga1 = A + (size_t)(mt * 128 + r1) * 512 + c1 * 8;
  const ushort* gw0 = W + (size_t)(nt * 128 + r0) * 512 + c0 * 8;
  const ushort* gw1 = W + (size_t)(nt * 128 + r1) * 512 + c1 * 8;
  ushort* la0 = ldsA + p0 * 8;
  ushort* la1 = ldsA + p1 * 8;
  ushort* lw0 = ldsW + p0 * 8;
  ushort* lw1 = ldsW + p1 * 8;

  int lane = t & 63, l15 = lane & 15, kg = lane >> 4;
  int wv = t >> 6;
  int mh = (wv >> 1) * 64, nh = (wv & 1) * 64;
  int swz = kg ^ ((l15 >> 1) & 3);
  const ushort* fa = ldsA + (mh + l15) * 32 + swz * 8;
  const ushort* fw = ldsW + (nh + l15) * 32 + swz * 8;

  for (int ks = 0; ks < 16; ++ks) {
    int ko = ks * 32;
    __builtin_amdgcn_global_load_lds(GPTR(ga0 + ko), SPTR(la0), 16, 0, 0);
    __builtin_amdgcn_global_load_lds(GPTR(ga1 + ko), SPTR(la1), 16, 0, 0);
    __builtin_amdgcn_global_load_lds(GPTR(gw0 + ko), SPTR(lw0), 16, 0, 0);
    __builtin_amdgcn_global_load_lds(GPTR(gw1 + ko), SPTR(lw1), 16, 0, 0);
    __syncthreads();
    bf16x8 af[4], wf[4];
#pragma unroll
    for (int i = 0; i < 4; ++i) af[i] = *(const bf16x8*)(fa + i * 512);
#pragma unroll
    for (int i = 0; i < 4; ++i) wf[i] = *(const bf16x8*)(fw + i * 512);
#pragma unroll
    for (int mi = 0; mi < 4; ++mi)
#pragma unroll
      for (int ni = 0; ni < 4; ++ni)
        acc[mi * 4 + ni] =
            __builtin_amdgcn_mfma_f32_16x16x32_bf16(af[mi], wf[ni], acc[mi * 4 + ni], 0, 0, 0);
    __syncthreads();
  }
}

// OUTMODE 0: C bf16 row-major [*,N]. 1: CT bf16 transposed CT[col*TM+row]
// (CT may be pre-offset). 2: Cf f32 row-major + bias.
template<int OUTMODE>
__device__ __forceinline__ void gemm128(const ushort* __restrict__ A,
                                        const ushort* __restrict__ W,
                                        ushort* __restrict__ C,
                                        ushort* __restrict__ CT,
                                        float* __restrict__ Cf,
                                        const float* __restrict__ bias,
                                        int mt, int nt, int N, long TM,
                                        ushort* lds) {
  f32x4 acc[16] = {{0,0,0,0},{0,0,0,0},{0,0,0,0},{0,0,0,0},
                   {0,0,0,0},{0,0,0,0},{0,0,0,0},{0,0,0,0},
                   {0,0,0,0},{0,0,0,0},{0,0,0,0},{0,0,0,0},
                   {0,0,0,0},{0,0,0,0},{0,0,0,0},{0,0,0,0}};
  gemm128_mac(A, W, mt, nt, lds, acc);

  int lane = threadIdx.x & 63, l15 = lane & 15, kg = lane >> 4;
  int wv = threadIdx.x >> 6;
  int Rw = mt * 128 + (wv >> 1) * 64;
  int Cw = nt * 128 + (wv & 1) * 64;
#pragma unroll
  for (int mi = 0; mi < 4; ++mi) {
    int row = Rw + mi * 16 + kg * 4;
#pragma unroll
    for (int ni = 0; ni < 4; ++ni) {
      f32x4 v = acc[mi * 4 + ni];
      int col = Cw + ni * 16 + l15;
      if (OUTMODE == 0) {
#pragma unroll
        for (int r = 0; r < 4; ++r) C[(size_t)(row + r) * N + col] = f2bf(v[r]);
      } else if (OUTMODE == 1) {
        ushort4 o = { f2bf(v[0]), f2bf(v[1]), f2bf(v[2]), f2bf(v[3]) };
        *(ushort4*)(CT + (long)col * TM + row) = o;
      } else {
        float bv = bias[col];
#pragma unroll
        for (int r = 0; r < 4; ++r) Cf[(size_t)(row + r) * N + col] = v[r] + bv;
      }
    }
  }
}

// Fused input GEMMs. blocks [0,288): qkv = x@qkv_w.T (24m x 12n tiles;
// n-tiles >=8 are self-V cols -> transposed into vselfT).
// [288,416): kctx = dx_ctx@k_w.T (32x4). [416,544): vctx^T (32x4).
__global__ __launch_bounds__(256) void gemm3(const ushort* __restrict__ xb,
                                             const ushort* __restrict__ dxb,
                                             const ushort* __restrict__ xcb,
                                             const ushort* __restrict__ qkvwb,
                                             const ushort* __restrict__ kwb,
                                             const ushort* __restrict__ vwb,
                                             ushort* __restrict__ qkv,
                                             ushort* __restrict__ vselfT,
                                             ushort* __restrict__ kctx,
                                             ushort* __restrict__ vctxT) {
  __shared__ ushort lds[8192];
  int blk = blockIdx.x;
  if (blk < 288) {
    int mt = blk % 24, nt = blk / 24;
    if (nt < 8)
      gemm128<0>(xb, qkvwb, qkv, nullptr, nullptr, nullptr, mt, nt, 1536, 0, lds);
    else
      gemm128<1>(xb, qkvwb, nullptr, vselfT - (size_t)1024 * 3072, nullptr, nullptr,
                 mt, nt, 1536, 3072, lds);
  } else if (blk < 416) {
    int r = blk - 288;
    gemm128<0>(dxb, kwb, kctx, nullptr, nullptr, nullptr, r % 32, r / 32, 512, 0, lds);
  } else {
    int r = blk - 416;
    gemm128<1>(xcb, vwb, nullptr, vctxT, nullptr, nullptr, r % 32, r / 32, 512, 4096, lds);
  }
}

__global__ __launch_bounds__(256) void gemm_proj(const ushort* __restrict__ aout,
                                                 const ushort* __restrict__ pwb,
                                                 const float* __restrict__ bias,
                                                 float* __restrict__ out) {
  __shared__ ushort lds[8192];
  int blk = blockIdx.x;  // 96 blocks: 24 mt x 4 nt
  gemm128<2>(aout, pwb, nullptr, nullptr, out, bias, blk % 24, blk / 24, 512, 0, lds);
}

// One attention tile: QK -> fixed-M exp -> Pt (LDS, double-buffered) -> PV.
// Scores s = z/8, z the raw bf16 dot; p = 2^(z*0.125*log2e - 16*log2e).
// Fixed M=16: no running max, no rescale -> loop-carried deps are acc + Lacc.
__device__ __forceinline__ void attn_tile(const ushort* __restrict__ kbase, int kstr,
                                          const ushort* __restrict__ vtb, int vtN,
                                          bf16x8 q0, bf16x8 q1,
                                          int l15, int kg,
                                          ushort* __restrict__ myPt,
                                          f32x4* acc, float& Lacc) {
  f32x4 s[4];
#pragma unroll
  for (int st = 0; st < 4; ++st) {
    const ushort* kp = kbase + (size_t)(st * 16 + l15) * kstr + kg * 8;
    bf16x8 k0 = *(const bf16x8*)kp;
    bf16x8 k1 = *(const bf16x8*)(kp + 32);
    f32x4 z = {0, 0, 0, 0};
    z = __builtin_amdgcn_mfma_f32_16x16x32_bf16(k0, q0, z, 0, 0, 0);
    z = __builtin_amdgcn_mfma_f32_16x16x32_bf16(k1, q1, z, 0, 0, 0);
    s[st] = z;
  }
#pragma unroll
  for (int st = 0; st < 4; ++st) {
    float p0 = __builtin_exp2f(fmaf(s[st][0], 0.18033688f, -23.0831206f));
    float p1 = __builtin_exp2f(fmaf(s[st][1], 0.18033688f, -23.0831206f));
    float p2 = __builtin_exp2f(fmaf(s[st][2], 0.18033688f, -23.0831206f));
    float p3 = __builtin_exp2f(fmaf(s[st][3], 0.18033688f, -23.0831206f));
    Lacc += (p0 + p1) + (p2 + p3);
    ushort4 pk = { f2bf(p0), f2bf(p1), f2bf(p2), f2bf(p3) };
    *(ushort4*)(myPt + l15 * 72 + st * 16 + kg * 4) = pk;
  }
#pragma unroll
  for (int kc = 0; kc < 2; ++kc) {
    bf16x8 pb = *(const bf16x8*)(myPt + l15 * 72 + kc * 32 + kg * 8);
#pragma unroll
    for (int d = 0; d < 4; ++d) {
      const ushort* vp = vtb + (size_t)(d * 16 + l15) * vtN + kc * 32 + kg * 8;
      bf16x8 vf = *(const bf16x8*)vp;
      acc[d] = __builtin_amdgcn_mfma_f32_16x16x32_bf16(vf, pb, acc[d], 0, 0, 0);
    }
  }
}

// Flash attention, fixed-M streaming softmax, 4-way split-K, half-frame blocks.
// Block = (b, h, t0, qh): 768 blocks x 512 threads = 2 q-groups x 4 key-splits.
// ks0: cross tiles 0-3 + self; ks1/2/3: tiles 4-7 / 8-11 / 12-15.
// Merge is a plain sum (constant M) through LDS.
__global__ __launch_bounds__(512) void flash_attn(const ushort* __restrict__ qkv,
                                                  const ushort* __restrict__ kctx,
                                                  const ushort* __restrict__ vctxT,
                                                  const ushort* __restrict__ vselfT,
                                                  const int* __restrict__ ctx_mask,
                                                  ushort* __restrict__ aout) {
  __shared__ ushort sm[18432];       // 36864 B: 8 waves x 2 Pt bufs x 1152;
                                     // post-loop aliased by 6 merge regions (26.1 KB)
  int blk = blockIdx.x;              // ((b*8+h)*12+t0)*2 + qh
  int qh = blk & 1;
  int rest = blk >> 1;
  int t0 = rest % NT0;
  int h  = (rest / NT0) % HH;
  int b  = rest / (NT0 * HH);
  int tid = threadIdx.x, wv = tid >> 6, lane = tid & 63;
  int qg = wv & 1, ks = wv >> 1;     // ks in [0,4)
  int l15 = lane & 15, kg = lane >> 4;

  int qrow = b * NQ + t0 * LL + qh * 32 + qg * 16 + l15;
  const ushort* qp = qkv + (size_t)qrow * 1536 + h * HD + kg * 8;
  bf16x8 q0 = *(const bf16x8*)qp;
  bf16x8 q1 = *(const bf16x8*)(qp + 32);

  f32x4 acc[4] = {{0,0,0,0},{0,0,0,0},{0,0,0,0},{0,0,0,0}};
  float Lacc = 0.f;
  ushort* Pt0 = sm + wv * 2304;

  // valid cross-tile list for this split (wave-uniform)
  int kts[4]; int nkt = 0;
#pragma unroll
  for (int ki = 0; ki < 4; ++ki) {
    int kt = ks * 4 + ki;
    if (ctx_mask[b * TT + kt] != 0 && kt != t0 + 4) kts[nkt++] = kt;
  }

  const ushort* vctxb = vctxT + (size_t)h * HD * (BB * NCTX) + b * NCTX;
  int buf = 0;
  for (int ki = 0; ki < nkt; ++ki) {
    int kt = kts[ki];
    attn_tile(kctx + (size_t)(b * NCTX + kt * LL) * CC + h * HD, CC,
              vctxb + kt * LL, BB * NCTX,
              q0, q1, l15, kg, Pt0 + buf * 1152, acc, Lacc);
    buf ^= 1;
  }
  if (ks == 0) {
    attn_tile(qkv + (size_t)(b * NQ + t0 * LL) * 1536 + CC + h * HD, 1536,
              vselfT + (size_t)h * HD * (BB * NQ) + b * NQ + t0 * LL, BB * NQ,
              q0, q1, l15, kg, Pt0 + buf * 1152, acc, Lacc);
  }

  // cross-lane L reduce (once)
  float Lr = Lacc;
  Lr += __shfl_xor(Lr, 16, 64);
  Lr += __shfl_xor(Lr, 32, 64);

  // ---- merge: ks1..3 publish (plain sums), ks0 adds & writes ----
  __syncthreads();
  float* fsm = (float*)sm;
  if (ks) {
    float* reg = fsm + (size_t)(qg * 3 + ks - 1) * 1088;  // 1024 acc + 64 L
#pragma unroll
    for (int d = 0; d < 4; ++d) *(f32x4*)(reg + lane * 16 + d * 4) = acc[d];
    reg[1024 + lane] = Lr;
  }
  __syncthreads();
  if (!ks) {
    float Ls = Lr;
    f32x4 o[4];
#pragma unroll
    for (int d = 0; d < 4; ++d) o[d] = acc[d];
#pragma unroll
    for (int j = 0; j < 3; ++j) {
      const float* reg = fsm + (size_t)(qg * 3 + j) * 1088;
      Ls += reg[1024 + lane];
#pragma unroll
      for (int d = 0; d < 4; ++d)
        o[d] += *(const f32x4*)(reg + lane * 16 + d * 4);
    }
    float inv = 1.f / Ls;
    int orow = b * NQ + t0 * LL + qh * 32 + qg * 16 + l15;
#pragma unroll
    for (int d = 0; d < 4; ++d) {
      ushort4 ov = { f2bf(o[d][0] * inv), f2bf(o[d][1] * inv),
                     f2bf(o[d][2] * inv), f2bf(o[d][3] * inv) };
      *(ushort4*)(aout + (size_t)orow * CC + h * HD + d * 16 + kg * 4) = ov;
    }
  }
}

extern "C" void kernel_launch(void* const* d_in, const int* in_sizes, int n_in,
                              void* d_out, int out_size, void* d_ws, size_t ws_size,
                              hipStream_t stream) {
  const float* x        = (const float*)d_in[0];
  const float* x_ctx    = (const float*)d_in[1];
  const float* dx_ctx   = (const float*)d_in[2];
  const int*   ctx_mask = (const int*)d_in[3];
  const float* qkv_w    = (const float*)d_in[4];
  const float* k_w      = (const float*)d_in[5];
  const float* v_w      = (const float*)d_in[6];
  const float* proj_w   = (const float*)d_in[7];
  const float* proj_b   = (const float*)d_in[8];
  float* out = (float*)d_out;

  ushort* ws = (ushort*)d_ws;   // element offsets (bf16)
  ushort* qkvwb  = ws;                    //  786432
  ushort* kwb    = ws + 786432;           //  262144
  ushort* vwb    = ws + 1048576;          //  262144
  ushort* pwb    = ws + 1310720;          //  262144
  ushort* xb     = ws + 1572864;          // 1572864  (3072x512)
  ushort* xcb    = ws + 3145728;          // 2097152  (4096x512)
  ushort* dxb    = ws + 5242880;          // 2097152  (4096x512)
  ushort* qkv    = ws + 7340032;          // 3072x1536
  ushort* kctx   = ws + 12058624;         // 4096x512
  ushort* vctxT  = ws + 14155776;         // 512x4096
  ushort* vselfT = ws + 16252928;         // 512x3072
  ushort* aout   = ws + 17825792;         // 3072x512  (end 19398656 el = 38.8MB)

  cvt_all<<<7168, 256, 0, stream>>>(qkv_w, k_w, v_w, proj_w, x, x_ctx, dx_ctx, ws);
  gemm3<<<544, 256, 0, stream>>>(xb, dxb, xcb, qkvwb, kwb, vwb,
                                 qkv, vselfT, kctx, vctxT);
  flash_attn<<<768, 512, 0, stream>>>(qkv, kctx, vctxT, vselfT, ctx_mask, aout);
  gemm_proj<<<96, 256, 0, stream>>>(aout, pwb, proj_b, out);
}

// Round 9
// 145.716 us; speedup vs baseline: 1.1044x; 1.0282x over previous
//
#include <hip/hip_runtime.h>
#include <hip/hip_bf16.h>

typedef __attribute__((ext_vector_type(8))) short bf16x8;
typedef __attribute__((ext_vector_type(4))) float f32x4;

#define BB 4
#define TT 16
#define NT0 12
#define LL 64
#define CC 512
#define HH 8
#define HD 64
#define NQ (NT0*LL)       // 768 queries per batch
#define NCTX (TT*LL)      // 1024 cross keys per batch

#define GPTR(x) ((__attribute__((address_space(1))) void*)(x))
#define SPTR(x) ((__attribute__((address_space(3))) void*)(x))
// waitcnt imm: vmcnt(n), lgkmcnt=15 (no wait), expcnt=7 (no wait)
#define VMCNT(n) (((n) & 15) | (((n) >> 4) << 14) | (7u << 4) | (0xFu << 8))

__device__ __forceinline__ float bf2f(ushort u) {
  union { unsigned int i; float f; } x; x.i = ((unsigned int)u) << 16; return x.f;
}
__device__ __forceinline__ ushort f2bf(float f) {
  union { float f; unsigned int i; } x; x.f = f;
  unsigned int r = x.i + 0x7fffu + ((x.i >> 16) & 1u);  // RNE
  return (ushort)(r >> 16);
}

// Convert f32 inputs -> bf16 workspace, layout [qkv_w|k_w|v_w|proj_w|x|x_ctx|dx_ctx]
__global__ __launch_bounds__(256) void cvt_all(const float* __restrict__ w0,
                                               const float* __restrict__ w1,
                                               const float* __restrict__ w2,
                                               const float* __restrict__ w3,
                                               const float* __restrict__ x,
                                               const float* __restrict__ xc,
                                               const float* __restrict__ dxc,
                                               ushort* __restrict__ dst) {
  long i = (long)blockIdx.x * 256 + threadIdx.x;  // float4 index, total 1835008
  const float* src; long off;
  if (i < 196608)       { src = w0;  off = 0; }
  else if (i < 262144)  { src = w1;  off = 196608; }
  else if (i < 327680)  { src = w2;  off = 262144; }
  else if (i < 393216)  { src = w3;  off = 327680; }
  else if (i < 786432)  { src = x;   off = 393216; }
  else if (i < 1310720) { src = xc;  off = 786432; }
  else                  { src = dxc; off = 1310720; }
  f32x4 v = *(const f32x4*)(src + (i - off) * 4);
  ushort4 o = { f2bf(v[0]), f2bf(v[1]), f2bf(v[2]), f2bf(v[3]) };
  *(ushort4*)(dst + i * 4) = o;
}

// ---------------------------------------------------------------------------
// 128x128-tile GEMM block body, BK=32, EXPLICIT LDS DOUBLE-BUFFER with raw
// s_barrier + manual vmcnt(4) so next iter's global_load_lds stay in flight
// across the barrier (the compiler's __syncthreads would drain vmcnt(0)).
// LDS: 2 bufs x (A 8KB + W 8KB) = 32 KB. Same XOR chunk swizzle as R5.
// ---------------------------------------------------------------------------
__device__ __forceinline__ void gemm128_mac(const ushort* __restrict__ A,
                                            const ushort* __restrict__ W,
                                            int mt, int nt, ushort* lds,
                                            f32x4* acc) {
  int t = threadIdx.x;
  int p0 = t, p1 = t + 256;
  int r0 = p0 >> 2, r1 = p1 >> 2;
  int c0 = (p0 & 3) ^ ((r0 >> 1) & 3);
  int c1 = (p1 & 3) ^ ((r1 >> 1) & 3);
  const ushort* ga0 = A + (size_t)(mt * 128 + r0) * 512 + c0 * 8;
  const ushort* ga1 = A + (size_t)(mt * 128 + r1) * 512 + c1 * 8;
  const ushort* gw0 = W + (size_t)(nt * 128 + r0) * 512 + c0 * 8;
  const ushort* gw1 = W + (size_t)(nt * 128 + r1) * 512 + c1 * 8;

  int lane = t & 63, l15 = lane & 15, kg = lane >> 4;
  int wv = t >> 6;
  int mh = (wv >> 1) * 64, nh = (wv & 1) * 64;
  int swz = kg ^ ((l15 >> 1) & 3);
  int faoff = (mh + l15) * 32 + swz * 8;   // within A tile
  int fwoff = (nh + l15) * 32 + swz * 8;   // within W tile

  // prologue: stage k-step 0 into buf0
  __builtin_amdgcn_global_load_lds(GPTR(ga0), SPTR(lds + p0 * 8), 16, 0, 0);
  __builtin_amdgcn_global_load_lds(GPTR(ga1), SPTR(lds + p1 * 8), 16, 0, 0);
  __builtin_amdgcn_global_load_lds(GPTR(gw0), SPTR(lds + 4096 + p0 * 8), 16, 0, 0);
  __builtin_amdgcn_global_load_lds(GPTR(gw1), SPTR(lds + 4096 + p1 * 8), 16, 0, 0);

#pragma unroll
  for (int ks = 0; ks < 16; ++ks) {
    int cur = (ks & 1) * 8192;
    int nxt = 8192 - cur;
    if (ks < 15) {
      int ko = (ks + 1) * 32;
      __builtin_amdgcn_global_load_lds(GPTR(ga0 + ko), SPTR(lds + nxt + p0 * 8), 16, 0, 0);
      __builtin_amdgcn_global_load_lds(GPTR(ga1 + ko), SPTR(lds + nxt + p1 * 8), 16, 0, 0);
      __builtin_amdgcn_global_load_lds(GPTR(gw0 + ko), SPTR(lds + nxt + 4096 + p0 * 8), 16, 0, 0);
      __builtin_amdgcn_global_load_lds(GPTR(gw1 + ko), SPTR(lds + nxt + 4096 + p1 * 8), 16, 0, 0);
      __builtin_amdgcn_s_waitcnt(VMCNT(4));   // cur buf complete; nxt in flight
    } else {
      __builtin_amdgcn_s_waitcnt(VMCNT(0));
    }
    asm volatile("" ::: "memory");
    __builtin_amdgcn_s_barrier();
    asm volatile("" ::: "memory");

    const ushort* fa = lds + cur + faoff;
    const ushort* fw = lds + cur + 4096 + fwoff;
    bf16x8 af[4], wf[4];
#pragma unroll
    for (int i = 0; i < 4; ++i) af[i] = *(const bf16x8*)(fa + i * 512);
#pragma unroll
    for (int i = 0; i < 4; ++i) wf[i] = *(const bf16x8*)(fw + i * 512);
#pragma unroll
    for (int mi = 0; mi < 4; ++mi)
#pragma unroll
      for (int ni = 0; ni < 4; ++ni)
        acc[mi * 4 + ni] =
            __builtin_amdgcn_mfma_f32_16x16x32_bf16(af[mi], wf[ni], acc[mi * 4 + ni], 0, 0, 0);

    // end-of-iter barrier: protects cur buf from being overwritten by the
    // loads issued at the top of the next iteration (lgkm drained by MFMA deps)
    asm volatile("" ::: "memory");
    __builtin_amdgcn_s_barrier();
    asm volatile("" ::: "memory");
  }
}

// OUTMODE 0: C bf16 row-major [*,N]. 1: CT bf16 transposed CT[col*TM+row]
// (CT may be pre-offset). 2: Cf f32 row-major + bias.
template<int OUTMODE>
__device__ __forceinline__ void gemm128(const ushort* __restrict__ A,
                                        const ushort* __restrict__ W,
                                        ushort* __restrict__ C,
                                        ushort* __restrict__ CT,
                                        float* __restrict__ Cf,
                                        const float* __restrict__ bias,
                                        int mt, int nt, int N, long TM,
                                        ushort* lds) {
  f32x4 acc[16] = {{0,0,0,0},{0,0,0,0},{0,0,0,0},{0,0,0,0},
                   {0,0,0,0},{0,0,0,0},{0,0,0,0},{0,0,0,0},
                   {0,0,0,0},{0,0,0,0},{0,0,0,0},{0,0,0,0},
                   {0,0,0,0},{0,0,0,0},{0,0,0,0},{0,0,0,0}};
  gemm128_mac(A, W, mt, nt, lds, acc);

  int lane = threadIdx.x & 63, l15 = lane & 15, kg = lane >> 4;
  int wv = threadIdx.x >> 6;
  int Rw = mt * 128 + (wv >> 1) * 64;
  int Cw = nt * 128 + (wv & 1) * 64;
#pragma unroll
  for (int mi = 0; mi < 4; ++mi) {
    int row = Rw + mi * 16 + kg * 4;
#pragma unroll
    for (int ni = 0; ni < 4; ++ni) {
      f32x4 v = acc[mi * 4 + ni];
      int col = Cw + ni * 16 + l15;
      if (OUTMODE == 0) {
#pragma unroll
        for (int r = 0; r < 4; ++r) C[(size_t)(row + r) * N + col] = f2bf(v[r]);
      } else if (OUTMODE == 1) {
        ushort4 o = { f2bf(v[0]), f2bf(v[1]), f2bf(v[2]), f2bf(v[3]) };
        *(ushort4*)(CT + (long)col * TM + row) = o;
      } else {
        float bv = bias[col];
#pragma unroll
        for (int r = 0; r < 4; ++r) Cf[(size_t)(row + r) * N + col] = v[r] + bv;
      }
    }
  }
}

// Fused input GEMMs. blocks [0,288): qkv = x@qkv_w.T (24m x 12n tiles;
// n-tiles >=8 are self-V cols -> transposed into vselfT).
// [288,416): kctx = dx_ctx@k_w.T (32x4). [416,544): vctx^T (32x4).
__global__ __launch_bounds__(256) void gemm3(const ushort* __restrict__ xb,
                                             const ushort* __restrict__ dxb,
                                             const ushort* __restrict__ xcb,
                                             const ushort* __restrict__ qkvwb,
                                             const ushort* __restrict__ kwb,
                                             const ushort* __restrict__ vwb,
                                             ushort* __restrict__ qkv,
                                             ushort* __restrict__ vselfT,
                                             ushort* __restrict__ kctx,
                                             ushort* __restrict__ vctxT) {
  __shared__ ushort lds[16384];
  int blk = blockIdx.x;
  if (blk < 288) {
    int mt = blk % 24, nt = blk / 24;
    if (nt < 8)
      gemm128<0>(xb, qkvwb, qkv, nullptr, nullptr, nullptr, mt, nt, 1536, 0, lds);
    else
      gemm128<1>(xb, qkvwb, nullptr, vselfT - (size_t)1024 * 3072, nullptr, nullptr,
                 mt, nt, 1536, 3072, lds);
  } else if (blk < 416) {
    int r = blk - 288;
    gemm128<0>(dxb, kwb, kctx, nullptr, nullptr, nullptr, r % 32, r / 32, 512, 0, lds);
  } else {
    int r = blk - 416;
    gemm128<1>(xcb, vwb, nullptr, vctxT, nullptr, nullptr, r % 32, r / 32, 512, 4096, lds);
  }
}

__global__ __launch_bounds__(256) void gemm_proj(const ushort* __restrict__ aout,
                                                 const ushort* __restrict__ pwb,
                                                 const float* __restrict__ bias,
                                                 float* __restrict__ out) {
  __shared__ ushort lds[16384];
  int blk = blockIdx.x;  // 96 blocks: 24 mt x 4 nt
  gemm128<2>(aout, pwb, nullptr, nullptr, out, bias, blk % 24, blk / 24, 512, 0, lds);
}

// One attention tile: QK -> fixed-M exp -> Pt (LDS, double-buffered) -> PV.
__device__ __forceinline__ void attn_tile(const ushort* __restrict__ kbase, int kstr,
                                          const ushort* __restrict__ vtb, int vtN,
                                          bf16x8 q0, bf16x8 q1,
                                          int l15, int kg,
                                          ushort* __restrict__ myPt,
                                          f32x4* acc, float& Lacc) {
  f32x4 s[4];
#pragma unroll
  for (int st = 0; st < 4; ++st) {
    const ushort* kp = kbase + (size_t)(st * 16 + l15) * kstr + kg * 8;
    bf16x8 k0 = *(const bf16x8*)kp;
    bf16x8 k1 = *(const bf16x8*)(kp + 32);
    f32x4 z = {0, 0, 0, 0};
    z = __builtin_amdgcn_mfma_f32_16x16x32_bf16(k0, q0, z, 0, 0, 0);
    z = __builtin_amdgcn_mfma_f32_16x16x32_bf16(k1, q1, z, 0, 0, 0);
    s[st] = z;
  }
#pragma unroll
  for (int st = 0; st < 4; ++st) {
    float p0 = __builtin_exp2f(fmaf(s[st][0], 0.18033688f, -23.0831206f));
    float p1 = __builtin_exp2f(fmaf(s[st][1], 0.18033688f, -23.0831206f));
    float p2 = __builtin_exp2f(fmaf(s[st][2], 0.18033688f, -23.0831206f));
    float p3 = __builtin_exp2f(fmaf(s[st][3], 0.18033688f, -23.0831206f));
    Lacc += (p0 + p1) + (p2 + p3);
    ushort4 pk = { f2bf(p0), f2bf(p1), f2bf(p2), f2bf(p3) };
    *(ushort4*)(myPt + l15 * 72 + st * 16 + kg * 4) = pk;
  }
#pragma unroll
  for (int kc = 0; kc < 2; ++kc) {
    bf16x8 pb = *(const bf16x8*)(myPt + l15 * 72 + kc * 32 + kg * 8);
#pragma unroll
    for (int d = 0; d < 4; ++d) {
      const ushort* vp = vtb + (size_t)(d * 16 + l15) * vtN + kc * 32 + kg * 8;
      bf16x8 vf = *(const bf16x8*)vp;
      acc[d] = __builtin_amdgcn_mfma_f32_16x16x32_bf16(vf, pb, acc[d], 0, 0, 0);
    }
  }
}

// Flash attention, fixed-M streaming softmax, 4-way split-K, half-frame blocks.
__global__ __launch_bounds__(512) void flash_attn(const ushort* __restrict__ qkv,
                                                  const ushort* __restrict__ kctx,
                                                  const ushort* __restrict__ vctxT,
                                                  const ushort* __restrict__ vselfT,
                                                  const int* __restrict__ ctx_mask,
                                                  ushort* __restrict__ aout) {
  __shared__ ushort sm[18432];       // 8 waves x 2 Pt bufs x 1152
  int blk = blockIdx.x;              // ((b*8+h)*12+t0)*2 + qh
  int qh = blk & 1;
  int rest = blk >> 1;
  int t0 = rest % NT0;
  int h  = (rest / NT0) % HH;
  int b  = rest / (NT0 * HH);
  int tid = threadIdx.x, wv = tid >> 6, lane = tid & 63;
  int qg = wv & 1, ks = wv >> 1;     // ks in [0,4)
  int l15 = lane & 15, kg = lane >> 4;

  int qrow = b * NQ + t0 * LL + qh * 32 + qg * 16 + l15;
  const ushort* qp = qkv + (size_t)qrow * 1536 + h * HD + kg * 8;
  bf16x8 q0 = *(const bf16x8*)qp;
  bf16x8 q1 = *(const bf16x8*)(qp + 32);

  f32x4 acc[4] = {{0,0,0,0},{0,0,0,0},{0,0,0,0},{0,0,0,0}};
  float Lacc = 0.f;
  ushort* Pt0 = sm + wv * 2304;

  int kts[4]; int nkt = 0;
#pragma unroll
  for (int ki = 0; ki < 4; ++ki) {
    int kt = ks * 4 + ki;
    if (ctx_mask[b * TT + kt] != 0 && kt != t0 + 4) kts[nkt++] = kt;
  }

  const ushort* vctxb = vctxT + (size_t)h * HD * (BB * NCTX) + b * NCTX;
  int buf = 0;
  for (int ki = 0; ki < nkt; ++ki) {
    int kt = kts[ki];
    attn_tile(kctx + (size_t)(b * NCTX + kt * LL) * CC + h * HD, CC,
              vctxb + kt * LL, BB * NCTX,
              q0, q1, l15, kg, Pt0 + buf * 1152, acc, Lacc);
    buf ^= 1;
  }
  if (ks == 0) {
    attn_tile(qkv + (size_t)(b * NQ + t0 * LL) * 1536 + CC + h * HD, 1536,
              vselfT + (size_t)h * HD * (BB * NQ) + b * NQ + t0 * LL, BB * NQ,
              q0, q1, l15, kg, Pt0 + buf * 1152, acc, Lacc);
  }

  float Lr = Lacc;
  Lr += __shfl_xor(Lr, 16, 64);
  Lr += __shfl_xor(Lr, 32, 64);

  __syncthreads();
  float* fsm = (float*)sm;
  if (ks) {
    float* reg = fsm + (size_t)(qg * 3 + ks - 1) * 1088;  // 1024 acc + 64 L
#pragma unroll
    for (int d = 0; d < 4; ++d) *(f32x4*)(reg + lane * 16 + d * 4) = acc[d];
    reg[1024 + lane] = Lr;
  }
  __syncthreads();
  if (!ks) {
    float Ls = Lr;
    f32x4 o[4];
#pragma unroll
    for (int d = 0; d < 4; ++d) o[d] = acc[d];
#pragma unroll
    for (int j = 0; j < 3; ++j) {
      const float* reg = fsm + (size_t)(qg * 3 + j) * 1088;
      Ls += reg[1024 + lane];
#pragma unroll
      for (int d = 0; d < 4; ++d)
        o[d] += *(const f32x4*)(reg + lane * 16 + d * 4);
    }
    float inv = 1.f / Ls;
    int orow = b * NQ + t0 * LL + qh * 32 + qg * 16 + l15;
#pragma unroll
    for (int d = 0; d < 4; ++d) {
      ushort4 ov = { f2bf(o[d][0] * inv), f2bf(o[d][1] * inv),
                     f2bf(o[d][2] * inv), f2bf(o[d][3] * inv) };
      *(ushort4*)(aout + (size_t)orow * CC + h * HD + d * 16 + kg * 4) = ov;
    }
  }
}

extern "C" void kernel_launch(void* const* d_in, const int* in_sizes, int n_in,
                              void* d_out, int out_size, void* d_ws, size_t ws_size,
                              hipStream_t stream) {
  const float* x        = (const float*)d_in[0];
  const float* x_ctx    = (const float*)d_in[1];
  const float* dx_ctx   = (const float*)d_in[2];
  const int*   ctx_mask = (const int*)d_in[3];
  const float* qkv_w    = (const float*)d_in[4];
  const float* k_w      = (const float*)d_in[5];
  const float* v_w      = (const float*)d_in[6];
  const float* proj_w   = (const float*)d_in[7];
  const float* proj_b   = (const float*)d_in[8];
  float* out = (float*)d_out;

  ushort* ws = (ushort*)d_ws;   // element offsets (bf16)
  ushort* qkvwb  = ws;                    //  786432
  ushort* kwb    = ws + 786432;           //  262144
  ushort* vwb    = ws + 1048576;          //  262144
  ushort* pwb    = ws + 1310720;          //  262144
  ushort* xb     = ws + 1572864;          // 1572864  (3072x512)
  ushort* xcb    = ws + 3145728;          // 2097152  (4096x512)
  ushort* dxb    = ws + 5242880;          // 2097152  (4096x512)
  ushort* qkv    = ws + 7340032;          // 3072x1536
  ushort* kctx   = ws + 12058624;         // 4096x512
  ushort* vctxT  = ws + 14155776;         // 512x4096
  ushort* vselfT = ws + 16252928;         // 512x3072
  ushort* aout   = ws + 17825792;         // 3072x512  (end 19398656 el = 38.8MB)

  cvt_all<<<7168, 256, 0, stream>>>(qkv_w, k_w, v_w, proj_w, x, x_ctx, dx_ctx, ws);
  gemm3<<<544, 256, 0, stream>>>(xb, dxb, xcb, qkvwb, kwb, vwb,
                                 qkv, vselfT, kctx, vctxT);
  flash_attn<<<768, 512, 0, stream>>>(qkv, kctx, vctxT, vselfT, ctx_mask, aout);
  gemm_proj<<<96, 256, 0, stream>>>(aout, pwb, proj_b, out);
}

// Round 10
// 144.136 us; speedup vs baseline: 1.1165x; 1.0110x over previous
//
#include <hip/hip_runtime.h>
#include <hip/hip_bf16.h>

typedef __attribute__((ext_vector_type(8))) short bf16x8;
typedef __attribute__((ext_vector_type(4))) float f32x4;

#define BB 4
#define TT 16
#define NT0 12
#define LL 64
#define CC 512
#define HH 8
#define HD 64
#define NQ (NT0*LL)       // 768 queries per batch
#define NCTX (TT*LL)      // 1024 cross keys per batch

#define GPTR(x) ((__attribute__((address_space(1))) void*)(x))
#define SPTR(x) ((__attribute__((address_space(3))) void*)(x))
// waitcnt imm: vmcnt(n) in [3:0] (n<=15 here), lgkmcnt=15 (no wait), expcnt=7 (no wait)
#define VMCNT(n) (((n) & 15) | (7u << 4) | (0xFu << 8))

__device__ __forceinline__ float bf2f(ushort u) {
  union { unsigned int i; float f; } x; x.i = ((unsigned int)u) << 16; return x.f;
}
__device__ __forceinline__ ushort f2bf(float f) {
  union { float f; unsigned int i; } x; x.f = f;
  unsigned int r = x.i + 0x7fffu + ((x.i >> 16) & 1u);  // RNE
  return (ushort)(r >> 16);
}

// Convert f32 inputs -> bf16 workspace, layout [qkv_w|k_w|v_w|proj_w|x|x_ctx|dx_ctx]
__global__ __launch_bounds__(256) void cvt_all(const float* __restrict__ w0,
                                               const float* __restrict__ w1,
                                               const float* __restrict__ w2,
                                               const float* __restrict__ w3,
                                               const float* __restrict__ x,
                                               const float* __restrict__ xc,
                                               const float* __restrict__ dxc,
                                               ushort* __restrict__ dst) {
  long i = (long)blockIdx.x * 256 + threadIdx.x;  // float4 index, total 1835008
  const float* src; long off;
  if (i < 196608)       { src = w0;  off = 0; }
  else if (i < 262144)  { src = w1;  off = 196608; }
  else if (i < 327680)  { src = w2;  off = 262144; }
  else if (i < 393216)  { src = w3;  off = 327680; }
  else if (i < 786432)  { src = x;   off = 393216; }
  else if (i < 1310720) { src = xc;  off = 786432; }
  else                  { src = dxc; off = 1310720; }
  f32x4 v = *(const f32x4*)(src + (i - off) * 4);
  ushort4 o = { f2bf(v[0]), f2bf(v[1]), f2bf(v[2]), f2bf(v[3]) };
  *(ushort4*)(dst + i * 4) = o;
}

// ---------------------------------------------------------------------------
// MTx128-tile GEMM block body (MT = 128 or 64), BK=32, TRIPLE-BUFFER depth-2:
// at iter ks, issue loads for ks+2, then s_waitcnt vmcnt(2L) (only ks's loads
// drained; ks+1/ks+2 stay in flight) + raw s_barrier. Same XOR chunk swizzle.
// LDS per buf: A MT*32 + W 128*32 bf16; 3 bufs.
// ---------------------------------------------------------------------------
template<int MT>
__device__ __forceinline__ void gemm_mac(const ushort* __restrict__ A,
                                         const ushort* __restrict__ W,
                                         int mt, int nt, ushort* lds,
                                         f32x4* acc) {
  constexpr int ACH = MT * 4;          // A chunks per buf (16B each)
  constexpr int ASZ = MT * 32;         // A ushorts per buf
  constexpr int BUF = ASZ + 4096;      // buf stride in ushorts
  constexpr int L   = (MT == 128) ? 4 : 3;  // loads per thread per stage

  int t = threadIdx.x;
  int pa0 = t, pa1 = t + 256;          // A chunk ids (pa1 only for MT=128)
  int ra0 = pa0 >> 2, ra1 = pa1 >> 2;
  int ca0 = (pa0 & 3) ^ ((ra0 >> 1) & 3);
  int ca1 = (pa1 & 3) ^ ((ra1 >> 1) & 3);
  int pw0 = t, pw1 = t + 256;          // W chunk ids
  const ushort* ga0 = A + (size_t)(mt * MT + ra0) * 512 + ca0 * 8;
  const ushort* ga1 = A + (size_t)(mt * MT + ra1) * 512 + ca1 * 8;
  const ushort* gw0 = W + (size_t)(nt * 128 + ra0) * 512 + ca0 * 8;
  const ushort* gw1 = W + (size_t)(nt * 128 + ra1) * 512 + ca1 * 8;

  int lane = t & 63, l15 = lane & 15, kg = lane >> 4;
  int wv = t >> 6;
  int mh = (wv >> 1) * (MT / 2), nh = (wv & 1) * 64;
  int swz = kg ^ ((l15 >> 1) & 3);
  int faoff = (mh + l15) * 32 + swz * 8;
  int fwoff = (nh + l15) * 32 + swz * 8;

  // stage k-step `ks` into buffer base `bb` (ushort offset)
  auto stage = [&](int ks, int bb) {
    int ko = ks * 32;
    __builtin_amdgcn_global_load_lds(GPTR(ga0 + ko), SPTR(lds + bb + pa0 * 8), 16, 0, 0);
    if (MT == 128)
      __builtin_amdgcn_global_load_lds(GPTR(ga1 + ko), SPTR(lds + bb + pa1 * 8), 16, 0, 0);
    __builtin_amdgcn_global_load_lds(GPTR(gw0 + ko), SPTR(lds + bb + ASZ + pw0 * 8), 16, 0, 0);
    __builtin_amdgcn_global_load_lds(GPTR(gw1 + ko), SPTR(lds + bb + ASZ + pw1 * 8), 16, 0, 0);
  };

  stage(0, 0);
  stage(1, BUF);

#pragma unroll
  for (int ks = 0; ks < 16; ++ks) {
    int cur = (ks % 3) * BUF;
    if (ks < 14) {
      stage(ks + 2, ((ks + 2) % 3) * BUF);
      __builtin_amdgcn_s_waitcnt(VMCNT(2 * L));
    } else if (ks == 14) {
      __builtin_amdgcn_s_waitcnt(VMCNT(L));
    } else {
      __builtin_amdgcn_s_waitcnt(VMCNT(0));
    }
    asm volatile("" ::: "memory");
    __builtin_amdgcn_s_barrier();
    asm volatile("" ::: "memory");

    const ushort* fa = lds + cur + faoff;
    const ushort* fw = lds + cur + ASZ + fwoff;
    bf16x8 af[MT / 32], wf[4];
#pragma unroll
    for (int i = 0; i < MT / 32; ++i) af[i] = *(const bf16x8*)(fa + i * 512);
#pragma unroll
    for (int i = 0; i < 4; ++i) wf[i] = *(const bf16x8*)(fw + i * 512);
#pragma unroll
    for (int mi = 0; mi < MT / 32; ++mi)
#pragma unroll
      for (int ni = 0; ni < 4; ++ni)
        acc[mi * 4 + ni] =
            __builtin_amdgcn_mfma_f32_16x16x32_bf16(af[mi], wf[ni], acc[mi * 4 + ni], 0, 0, 0);

    asm volatile("" ::: "memory");
    __builtin_amdgcn_s_barrier();
    asm volatile("" ::: "memory");
  }
}

// OUTMODE 0: C bf16 row-major [*,N]. 1: CT bf16 transposed CT[col*TM+row]
// (CT may be pre-offset). 2: Cf f32 row-major + bias.
template<int MT, int OUTMODE>
__device__ __forceinline__ void gemm_body(const ushort* __restrict__ A,
                                          const ushort* __restrict__ W,
                                          ushort* __restrict__ C,
                                          ushort* __restrict__ CT,
                                          float* __restrict__ Cf,
                                          const float* __restrict__ bias,
                                          int mt, int nt, int N, long TM,
                                          ushort* lds) {
  f32x4 acc[(MT / 32) * 4];
#pragma unroll
  for (int i = 0; i < (MT / 32) * 4; ++i) acc[i] = (f32x4){0, 0, 0, 0};
  gemm_mac<MT>(A, W, mt, nt, lds, acc);

  int lane = threadIdx.x & 63, l15 = lane & 15, kg = lane >> 4;
  int wv = threadIdx.x >> 6;
  int Rw = mt * MT + (wv >> 1) * (MT / 2);
  int Cw = nt * 128 + (wv & 1) * 64;
#pragma unroll
  for (int mi = 0; mi < MT / 32; ++mi) {
    int row = Rw + mi * 16 + kg * 4;
#pragma unroll
    for (int ni = 0; ni < 4; ++ni) {
      f32x4 v = acc[mi * 4 + ni];
      int col = Cw + ni * 16 + l15;
      if (OUTMODE == 0) {
#pragma unroll
        for (int r = 0; r < 4; ++r) C[(size_t)(row + r) * N + col] = f2bf(v[r]);
      } else if (OUTMODE == 1) {
        ushort4 o = { f2bf(v[0]), f2bf(v[1]), f2bf(v[2]), f2bf(v[3]) };
        *(ushort4*)(CT + (long)col * TM + row) = o;
      } else {
        float bv = bias[col];
#pragma unroll
        for (int r = 0; r < 4; ++r) Cf[(size_t)(row + r) * N + col] = v[r] + bv;
      }
    }
  }
}

// Fused input GEMMs. blocks [0,288): qkv = x@qkv_w.T (24m x 12n tiles;
// n-tiles >=8 are self-V cols -> transposed into vselfT).
// [288,416): kctx = dx_ctx@k_w.T (32x4). [416,544): vctx^T (32x4).
__global__ __launch_bounds__(256) void gemm3(const ushort* __restrict__ xb,
                                             const ushort* __restrict__ dxb,
                                             const ushort* __restrict__ xcb,
                                             const ushort* __restrict__ qkvwb,
                                             const ushort* __restrict__ kwb,
                                             const ushort* __restrict__ vwb,
                                             ushort* __restrict__ qkv,
                                             ushort* __restrict__ vselfT,
                                             ushort* __restrict__ kctx,
                                             ushort* __restrict__ vctxT) {
  __shared__ ushort lds[24576];   // 3 bufs x (A 8KB + W 8KB) = 48 KB
  int blk = blockIdx.x;
  if (blk < 288) {
    int mt = blk % 24, nt = blk / 24;
    if (nt < 8)
      gemm_body<128, 0>(xb, qkvwb, qkv, nullptr, nullptr, nullptr, mt, nt, 1536, 0, lds);
    else
      gemm_body<128, 1>(xb, qkvwb, nullptr, vselfT - (size_t)1024 * 3072, nullptr, nullptr,
                        mt, nt, 1536, 3072, lds);
  } else if (blk < 416) {
    int r = blk - 288;
    gemm_body<128, 0>(dxb, kwb, kctx, nullptr, nullptr, nullptr, r % 32, r / 32, 512, 0, lds);
  } else {
    int r = blk - 416;
    gemm_body<128, 1>(xcb, vwb, nullptr, vctxT, nullptr, nullptr, r % 32, r / 32, 512, 4096, lds);
  }
}

// proj: 64-row tiles -> 192 blocks (48 mt x 4 nt), 2x CU coverage vs 128-row.
__global__ __launch_bounds__(256) void gemm_proj(const ushort* __restrict__ aout,
                                                 const ushort* __restrict__ pwb,
                                                 const float* __restrict__ bias,
                                                 float* __restrict__ out) {
  __shared__ ushort lds[18432];   // 3 bufs x (A 4KB + W 8KB) = 36 KB
  int blk = blockIdx.x;
  gemm_body<64, 2>(aout, pwb, nullptr, nullptr, out, bias, blk % 48, blk / 48, 512, 0, lds);
}

// One attention tile: QK -> fixed-M exp -> Pt (LDS, double-buffered) -> PV.
__device__ __forceinline__ void attn_tile(const ushort* __restrict__ kbase, int kstr,
                                          const ushort* __restrict__ vtb, int vtN,
                                          bf16x8 q0, bf16x8 q1,
                                          int l15, int kg,
                                          ushort* __restrict__ myPt,
                                          f32x4* acc, float& Lacc) {
  f32x4 s[4];
#pragma unroll
  for (int st = 0; st < 4; ++st) {
    const ushort* kp = kbase + (size_t)(st * 16 + l15) * kstr + kg * 8;
    bf16x8 k0 = *(const bf16x8*)kp;
    bf16x8 k1 = *(const bf16x8*)(kp + 32);
    f32x4 z = {0, 0, 0, 0};
    z = __builtin_amdgcn_mfma_f32_16x16x32_bf16(k0, q0, z, 0, 0, 0);
    z = __builtin_amdgcn_mfma_f32_16x16x32_bf16(k1, q1, z, 0, 0, 0);
    s[st] = z;
  }
#pragma unroll
  for (int st = 0; st < 4; ++st) {
    float p0 = __builtin_exp2f(fmaf(s[st][0], 0.18033688f, -23.0831206f));
    float p1 = __builtin_exp2f(fmaf(s[st][1], 0.18033688f, -23.0831206f));
    float p2 = __builtin_exp2f(fmaf(s[st][2], 0.18033688f, -23.0831206f));
    float p3 = __builtin_exp2f(fmaf(s[st][3], 0.18033688f, -23.0831206f));
    Lacc += (p0 + p1) + (p2 + p3);
    ushort4 pk = { f2bf(p0), f2bf(p1), f2bf(p2), f2bf(p3) };
    *(ushort4*)(myPt + l15 * 72 + st * 16 + kg * 4) = pk;
  }
#pragma unroll
  for (int kc = 0; kc < 2; ++kc) {
    bf16x8 pb = *(const bf16x8*)(myPt + l15 * 72 + kc * 32 + kg * 8);
#pragma unroll
    for (int d = 0; d < 4; ++d) {
      const ushort* vp = vtb + (size_t)(d * 16 + l15) * vtN + kc * 32 + kg * 8;
      bf16x8 vf = *(const bf16x8*)vp;
      acc[d] = __builtin_amdgcn_mfma_f32_16x16x32_bf16(vf, pb, acc[d], 0, 0, 0);
    }
  }
}

// Flash attention, fixed-M streaming softmax, 4-way split-K, half-frame blocks.
__global__ __launch_bounds__(512) void flash_attn(const ushort* __restrict__ qkv,
                                                  const ushort* __restrict__ kctx,
                                                  const ushort* __restrict__ vctxT,
                                                  const ushort* __restrict__ vselfT,
                                                  const int* __restrict__ ctx_mask,
                                                  ushort* __restrict__ aout) {
  __shared__ ushort sm[18432];       // 8 waves x 2 Pt bufs x 1152
  int blk = blockIdx.x;              // ((b*8+h)*12+t0)*2 + qh
  int qh = blk & 1;
  int rest = blk >> 1;
  int t0 = rest % NT0;
  int h  = (rest / NT0) % HH;
  int b  = rest / (NT0 * HH);
  int tid = threadIdx.x, wv = tid >> 6, lane = tid & 63;
  int qg = wv & 1, ks = wv >> 1;     // ks in [0,4)
  int l15 = lane & 15, kg = lane >> 4;

  int qrow = b * NQ + t0 * LL + qh * 32 + qg * 16 + l15;
  const ushort* qp = qkv + (size_t)qrow * 1536 + h * HD + kg * 8;
  bf16x8 q0 = *(const bf16x8*)qp;
  bf16x8 q1 = *(const bf16x8*)(qp + 32);

  f32x4 acc[4] = {{0,0,0,0},{0,0,0,0},{0,0,0,0},{0,0,0,0}};
  float Lacc = 0.f;
  ushort* Pt0 = sm + wv * 2304;

  int kts[4]; int nkt = 0;
#pragma unroll
  for (int ki = 0; ki < 4; ++ki) {
    int kt = ks * 4 + ki;
    if (ctx_mask[b * TT + kt] != 0 && kt != t0 + 4) kts[nkt++] = kt;
  }

  const ushort* vctxb = vctxT + (size_t)h * HD * (BB * NCTX) + b * NCTX;
  int buf = 0;
  for (int ki = 0; ki < nkt; ++ki) {
    int kt = kts[ki];
    attn_tile(kctx + (size_t)(b * NCTX + kt * LL) * CC + h * HD, CC,
              vctxb + kt * LL, BB * NCTX,
              q0, q1, l15, kg, Pt0 + buf * 1152, acc, Lacc);
    buf ^= 1;
  }
  if (ks == 0) {
    attn_tile(qkv + (size_t)(b * NQ + t0 * LL) * 1536 + CC + h * HD, 1536,
              vselfT + (size_t)h * HD * (BB * NQ) + b * NQ + t0 * LL, BB * NQ,
              q0, q1, l15, kg, Pt0 + buf * 1152, acc, Lacc);
  }

  float Lr = Lacc;
  Lr += __shfl_xor(Lr, 16, 64);
  Lr += __shfl_xor(Lr, 32, 64);

  __syncthreads();
  float* fsm = (float*)sm;
  if (ks) {
    float* reg = fsm + (size_t)(qg * 3 + ks - 1) * 1088;  // 1024 acc + 64 L
#pragma unroll
    for (int d = 0; d < 4; ++d) *(f32x4*)(reg + lane * 16 + d * 4) = acc[d];
    reg[1024 + lane] = Lr;
  }
  __syncthreads();
  if (!ks) {
    float Ls = Lr;
    f32x4 o[4];
#pragma unroll
    for (int d = 0; d < 4; ++d) o[d] = acc[d];
#pragma unroll
    for (int j = 0; j < 3; ++j) {
      const float* reg = fsm + (size_t)(qg * 3 + j) * 1088;
      Ls += reg[1024 + lane];
#pragma unroll
      for (int d = 0; d < 4; ++d)
        o[d] += *(const f32x4*)(reg + lane * 16 + d * 4);
    }
    float inv = 1.f / Ls;
    int orow = b * NQ + t0 * LL + qh * 32 + qg * 16 + l15;
#pragma unroll
    for (int d = 0; d < 4; ++d) {
      ushort4 ov = { f2bf(o[d][0] * inv), f2bf(o[d][1] * inv),
                     f2bf(o[d][2] * inv), f2bf(o[d][3] * inv) };
      *(ushort4*)(aout + (size_t)orow * CC + h * HD + d * 16 + kg * 4) = ov;
    }
  }
}

extern "C" void kernel_launch(void* const* d_in, const int* in_sizes, int n_in,
                              void* d_out, int out_size, void* d_ws, size_t ws_size,
                              hipStream_t stream) {
  const float* x        = (const float*)d_in[0];
  const float* x_ctx    = (const float*)d_in[1];
  const float* dx_ctx   = (const float*)d_in[2];
  const int*   ctx_mask = (const int*)d_in[3];
  const float* qkv_w    = (const float*)d_in[4];
  const float* k_w      = (const float*)d_in[5];
  const float* v_w      = (const float*)d_in[6];
  const float* proj_w   = (const float*)d_in[7];
  const float* proj_b   = (const float*)d_in[8];
  float* out = (float*)d_out;

  ushort* ws = (ushort*)d_ws;   // element offsets (bf16)
  ushort* qkvwb  = ws;                    //  786432
  ushort* kwb    = ws + 786432;           //  262144
  ushort* vwb    = ws + 1048576;          //  262144
  ushort* pwb    = ws + 1310720;          //  262144
  ushort* xb     = ws + 1572864;          // 1572864  (3072x512)
  ushort* xcb    = ws + 3145728;          // 2097152  (4096x512)
  ushort* dxb    = ws + 5242880;          // 2097152  (4096x512)
  ushort* qkv    = ws + 7340032;          // 3072x1536
  ushort* kctx   = ws + 12058624;         // 4096x512
  ushort* vctxT  = ws + 14155776;         // 512x4096
  ushort* vselfT = ws + 16252928;         // 512x3072
  ushort* aout   = ws + 17825792;         // 3072x512  (end 19398656 el = 38.8MB)

  cvt_all<<<7168, 256, 0, stream>>>(qkv_w, k_w, v_w, proj_w, x, x_ctx, dx_ctx, ws);
  gemm3<<<544, 256, 0, stream>>>(xb, dxb, xcb, qkvwb, kwb, vwb,
                                 qkv, vselfT, kctx, vctxT);
  flash_attn<<<768, 512, 0, stream>>>(qkv, kctx, vctxT, vselfT, ctx_mask, aout);
  gemm_proj<<<192, 256, 0, stream>>>(aout, pwb, proj_b, out);
}

// Round 11
// 139.683 us; speedup vs baseline: 1.1521x; 1.0319x over previous
//
#include <hip/hip_runtime.h>
#include <hip/hip_bf16.h>

typedef __attribute__((ext_vector_type(8))) short bf16x8;
typedef __attribute__((ext_vector_type(4))) float f32x4;

#define BB 4
#define TT 16
#define NT0 12
#define LL 64
#define CC 512
#define HH 8
#define HD 64
#define NQ (NT0*LL)       // 768 queries per batch
#define NCTX (TT*LL)      // 1024 cross keys per batch

#define GPTR(x) ((__attribute__((address_space(1))) void*)(x))
#define SPTR(x) ((__attribute__((address_space(3))) void*)(x))
// waitcnt imm: vmcnt(n) in [3:0] (n<=15 here), lgkmcnt=15 (no wait), expcnt=7 (no wait)
#define VMCNT(n) (((n) & 15) | (7u << 4) | (0xFu << 8))

__device__ __forceinline__ float bf2f(ushort u) {
  union { unsigned int i; float f; } x; x.i = ((unsigned int)u) << 16; return x.f;
}
__device__ __forceinline__ ushort f2bf(float f) {
  union { float f; unsigned int i; } x; x.f = f;
  unsigned int r = x.i + 0x7fffu + ((x.i >> 16) & 1u);  // RNE
  return (ushort)(r >> 16);
}

// Convert f32 inputs -> bf16 workspace, layout [qkv_w|k_w|v_w|proj_w|x|x_ctx|dx_ctx]
__global__ __launch_bounds__(256) void cvt_all(const float* __restrict__ w0,
                                               const float* __restrict__ w1,
                                               const float* __restrict__ w2,
                                               const float* __restrict__ w3,
                                               const float* __restrict__ x,
                                               const float* __restrict__ xc,
                                               const float* __restrict__ dxc,
                                               ushort* __restrict__ dst) {
  long i = (long)blockIdx.x * 256 + threadIdx.x;  // float4 index, total 1835008
  const float* src; long off;
  if (i < 196608)       { src = w0;  off = 0; }
  else if (i < 262144)  { src = w1;  off = 196608; }
  else if (i < 327680)  { src = w2;  off = 262144; }
  else if (i < 393216)  { src = w3;  off = 327680; }
  else if (i < 786432)  { src = x;   off = 393216; }
  else if (i < 1310720) { src = xc;  off = 786432; }
  else                  { src = dxc; off = 1310720; }
  f32x4 v = *(const f32x4*)(src + (i - off) * 4);
  ushort4 o = { f2bf(v[0]), f2bf(v[1]), f2bf(v[2]), f2bf(v[3]) };
  *(ushort4*)(dst + i * 4) = o;
}

// ---------------------------------------------------------------------------
// MTx128-tile GEMM block body (MT = 128 or 64), BK=32, TRIPLE-BUFFER depth-2
// (R10-proven): issue ks+2's loads, wait vmcnt(2L), raw s_barrier.
// ---------------------------------------------------------------------------
template<int MT>
__device__ __forceinline__ void gemm_mac(const ushort* __restrict__ A,
                                         const ushort* __restrict__ W,
                                         int mt, int nt, ushort* lds,
                                         f32x4* acc) {
  constexpr int ASZ = MT * 32;         // A ushorts per buf
  constexpr int BUF = ASZ + 4096;      // buf stride in ushorts
  constexpr int L   = (MT == 128) ? 4 : 3;  // loads per thread per stage

  int t = threadIdx.x;
  int pa0 = t, pa1 = t + 256;
  int ra0 = pa0 >> 2, ra1 = pa1 >> 2;
  int ca0 = (pa0 & 3) ^ ((ra0 >> 1) & 3);
  int ca1 = (pa1 & 3) ^ ((ra1 >> 1) & 3);
  const ushort* ga0 = A + (size_t)(mt * MT + ra0) * 512 + ca0 * 8;
  const ushort* ga1 = A + (size_t)(mt * MT + ra1) * 512 + ca1 * 8;
  const ushort* gw0 = W + (size_t)(nt * 128 + ra0) * 512 + ca0 * 8;
  const ushort* gw1 = W + (size_t)(nt * 128 + ra1) * 512 + ca1 * 8;

  int lane = t & 63, l15 = lane & 15, kg = lane >> 4;
  int wv = t >> 6;
  int mh = (wv >> 1) * (MT / 2), nh = (wv & 1) * 64;
  int swz = kg ^ ((l15 >> 1) & 3);
  int faoff = (mh + l15) * 32 + swz * 8;
  int fwoff = (nh + l15) * 32 + swz * 8;

  auto stage = [&](int ks, int bb) {
    int ko = ks * 32;
    __builtin_amdgcn_global_load_lds(GPTR(ga0 + ko), SPTR(lds + bb + pa0 * 8), 16, 0, 0);
    if (MT == 128)
      __builtin_amdgcn_global_load_lds(GPTR(ga1 + ko), SPTR(lds + bb + pa1 * 8), 16, 0, 0);
    __builtin_amdgcn_global_load_lds(GPTR(gw0 + ko), SPTR(lds + bb + ASZ + pa0 * 8), 16, 0, 0);
    __builtin_amdgcn_global_load_lds(GPTR(gw1 + ko), SPTR(lds + bb + ASZ + pa1 * 8), 16, 0, 0);
  };

  stage(0, 0);
  stage(1, BUF);

#pragma unroll
  for (int ks = 0; ks < 16; ++ks) {
    int cur = (ks % 3) * BUF;
    if (ks < 14) {
      stage(ks + 2, ((ks + 2) % 3) * BUF);
      __builtin_amdgcn_s_waitcnt(VMCNT(2 * L));
    } else if (ks == 14) {
      __builtin_amdgcn_s_waitcnt(VMCNT(L));
    } else {
      __builtin_amdgcn_s_waitcnt(VMCNT(0));
    }
    asm volatile("" ::: "memory");
    __builtin_amdgcn_s_barrier();
    asm volatile("" ::: "memory");

    const ushort* fa = lds + cur + faoff;
    const ushort* fw = lds + cur + ASZ + fwoff;
    bf16x8 af[MT / 32], wf[4];
#pragma unroll
    for (int i = 0; i < MT / 32; ++i) af[i] = *(const bf16x8*)(fa + i * 512);
#pragma unroll
    for (int i = 0; i < 4; ++i) wf[i] = *(const bf16x8*)(fw + i * 512);
#pragma unroll
    for (int mi = 0; mi < MT / 32; ++mi)
#pragma unroll
      for (int ni = 0; ni < 4; ++ni)
        acc[mi * 4 + ni] =
            __builtin_amdgcn_mfma_f32_16x16x32_bf16(af[mi], wf[ni], acc[mi * 4 + ni], 0, 0, 0);

    asm volatile("" ::: "memory");
    __builtin_amdgcn_s_barrier();
    asm volatile("" ::: "memory");
  }
}

// OUTMODE 0: C bf16 row-major [*,N]. 1: CT bf16 transposed CT[col*TM+row]
// (CT may be pre-offset). 2: Cf f32 row-major + bias.
template<int MT, int OUTMODE>
__device__ __forceinline__ void gemm_body(const ushort* __restrict__ A,
                                          const ushort* __restrict__ W,
                                          ushort* __restrict__ C,
                                          ushort* __restrict__ CT,
                                          float* __restrict__ Cf,
                                          const float* __restrict__ bias,
                                          int mt, int nt, int N, long TM,
                                          ushort* lds) {
  f32x4 acc[(MT / 32) * 4];
#pragma unroll
  for (int i = 0; i < (MT / 32) * 4; ++i) acc[i] = (f32x4){0, 0, 0, 0};
  gemm_mac<MT>(A, W, mt, nt, lds, acc);

  int lane = threadIdx.x & 63, l15 = lane & 15, kg = lane >> 4;
  int wv = threadIdx.x >> 6;
  int Rw = mt * MT + (wv >> 1) * (MT / 2);
  int Cw = nt * 128 + (wv & 1) * 64;
#pragma unroll
  for (int mi = 0; mi < MT / 32; ++mi) {
    int row = Rw + mi * 16 + kg * 4;
#pragma unroll
    for (int ni = 0; ni < 4; ++ni) {
      f32x4 v = acc[mi * 4 + ni];
      int col = Cw + ni * 16 + l15;
      if (OUTMODE == 0) {
#pragma unroll
        for (int r = 0; r < 4; ++r) C[(size_t)(row + r) * N + col] = f2bf(v[r]);
      } else if (OUTMODE == 1) {
        ushort4 o = { f2bf(v[0]), f2bf(v[1]), f2bf(v[2]), f2bf(v[3]) };
        *(ushort4*)(CT + (long)col * TM + row) = o;
      } else {
        float bv = bias[col];
#pragma unroll
        for (int r = 0; r < 4; ++r) Cf[(size_t)(row + r) * N + col] = v[r] + bv;
      }
    }
  }
}

// Fused input GEMMs. blocks [0,288): qkv = x@qkv_w.T (24m x 12n tiles;
// n-tiles >=8 are self-V cols -> transposed into vselfT).
// [288,416): kctx = dx_ctx@k_w.T (32x4). [416,544): vctx^T (32x4).
__global__ __launch_bounds__(256) void gemm3(const ushort* __restrict__ xb,
                                             const ushort* __restrict__ dxb,
                                             const ushort* __restrict__ xcb,
                                             const ushort* __restrict__ qkvwb,
                                             const ushort* __restrict__ kwb,
                                             const ushort* __restrict__ vwb,
                                             ushort* __restrict__ qkv,
                                             ushort* __restrict__ vselfT,
                                             ushort* __restrict__ kctx,
                                             ushort* __restrict__ vctxT) {
  __shared__ ushort lds[24576];   // 3 bufs x (A 8KB + W 8KB) = 48 KB
  int blk = blockIdx.x;
  if (blk < 288) {
    int mt = blk % 24, nt = blk / 24;
    if (nt < 8)
      gemm_body<128, 0>(xb, qkvwb, qkv, nullptr, nullptr, nullptr, mt, nt, 1536, 0, lds);
    else
      gemm_body<128, 1>(xb, qkvwb, nullptr, vselfT - (size_t)1024 * 3072, nullptr, nullptr,
                        mt, nt, 1536, 3072, lds);
  } else if (blk < 416) {
    int r = blk - 288;
    gemm_body<128, 0>(dxb, kwb, kctx, nullptr, nullptr, nullptr, r % 32, r / 32, 512, 0, lds);
  } else {
    int r = blk - 416;
    gemm_body<128, 1>(xcb, vwb, nullptr, vctxT, nullptr, nullptr, r % 32, r / 32, 512, 4096, lds);
  }
}

// proj: 64-row tiles -> 192 blocks (48 mt x 4 nt).
__global__ __launch_bounds__(256) void gemm_proj(const ushort* __restrict__ aout,
                                                 const ushort* __restrict__ pwb,
                                                 const float* __restrict__ bias,
                                                 float* __restrict__ out) {
  __shared__ ushort lds[18432];   // 3 bufs x (A 4KB + W 8KB) = 36 KB
  int blk = blockIdx.x;
  gemm_body<64, 2>(aout, pwb, nullptr, nullptr, out, bias, blk % 48, blk / 48, 512, 0, lds);
}

// One attention tile for a 32-query wave: one K/V fragment stream feeds TWO
// 16-query S^T/PV chains (halves K/V L2 traffic per query).
__device__ __forceinline__ void attn_tile32(const ushort* __restrict__ kbase, int kstr,
                                            const ushort* __restrict__ vtb, int vtN,
                                            bf16x8 qa0, bf16x8 qa1,
                                            bf16x8 qb0, bf16x8 qb1,
                                            int l15, int kg,
                                            ushort* __restrict__ Pt,
                                            f32x4 (*acc)[4], float* Lacc) {
  f32x4 s[2][4];
#pragma unroll
  for (int st = 0; st < 4; ++st) {
    const ushort* kp = kbase + (size_t)(st * 16 + l15) * kstr + kg * 8;
    bf16x8 k0 = *(const bf16x8*)kp;
    bf16x8 k1 = *(const bf16x8*)(kp + 32);
    f32x4 z0 = {0, 0, 0, 0}, z1 = {0, 0, 0, 0};
    z0 = __builtin_amdgcn_mfma_f32_16x16x32_bf16(k0, qa0, z0, 0, 0, 0);
    z0 = __builtin_amdgcn_mfma_f32_16x16x32_bf16(k1, qa1, z0, 0, 0, 0);
    z1 = __builtin_amdgcn_mfma_f32_16x16x32_bf16(k0, qb0, z1, 0, 0, 0);
    z1 = __builtin_amdgcn_mfma_f32_16x16x32_bf16(k1, qb1, z1, 0, 0, 0);
    s[0][st] = z0;
    s[1][st] = z1;
  }
#pragma unroll
  for (int qf = 0; qf < 2; ++qf) {
#pragma unroll
    for (int st = 0; st < 4; ++st) {
      float p0 = __builtin_exp2f(fmaf(s[qf][st][0], 0.18033688f, -23.0831206f));
      float p1 = __builtin_exp2f(fmaf(s[qf][st][1], 0.18033688f, -23.0831206f));
      float p2 = __builtin_exp2f(fmaf(s[qf][st][2], 0.18033688f, -23.0831206f));
      float p3 = __builtin_exp2f(fmaf(s[qf][st][3], 0.18033688f, -23.0831206f));
      Lacc[qf] += (p0 + p1) + (p2 + p3);
      ushort4 pk = { f2bf(p0), f2bf(p1), f2bf(p2), f2bf(p3) };
      *(ushort4*)(Pt + qf * 1152 + l15 * 72 + st * 16 + kg * 4) = pk;
    }
  }
#pragma unroll
  for (int kc = 0; kc < 2; ++kc) {
    bf16x8 pb0 = *(const bf16x8*)(Pt + l15 * 72 + kc * 32 + kg * 8);
    bf16x8 pb1 = *(const bf16x8*)(Pt + 1152 + l15 * 72 + kc * 32 + kg * 8);
#pragma unroll
    for (int d = 0; d < 4; ++d) {
      const ushort* vp = vtb + (size_t)(d * 16 + l15) * vtN + kc * 32 + kg * 8;
      bf16x8 vf = *(const bf16x8*)vp;
      acc[0][d] = __builtin_amdgcn_mfma_f32_16x16x32_bf16(vf, pb0, acc[0][d], 0, 0, 0);
      acc[1][d] = __builtin_amdgcn_mfma_f32_16x16x32_bf16(vf, pb1, acc[1][d], 0, 0, 0);
    }
  }
}

// Flash attention, fixed-M streaming softmax, 4-way split-K, 32-query waves.
// Block = (b, h, t0): 384 blocks x 512 threads = 2 q-halves x 4 key-splits.
// ks0: cross tiles 0-3 + self; ks1/2/3: tiles 4-7 / 8-11 / 12-15.
__global__ __launch_bounds__(512, 4) void flash_attn(const ushort* __restrict__ qkv,
                                                     const ushort* __restrict__ kctx,
                                                     const ushort* __restrict__ vctxT,
                                                     const ushort* __restrict__ vselfT,
                                                     const int* __restrict__ ctx_mask,
                                                     ushort* __restrict__ aout) {
  __shared__ float smem[13056];      // 52.2 KB; Pt strips (36 KB) alias low part
  int blk = blockIdx.x;              // b*96 + h*12 + t0
  int t0 = blk % NT0;
  int h  = (blk / NT0) % HH;
  int b  = blk / (NT0 * HH);
  int tid = threadIdx.x, wv = tid >> 6, lane = tid & 63;
  int qg = wv >> 2, ks = wv & 3;     // qg: 32-query half; ks: key split
  int l15 = lane & 15, kg = lane >> 4;

  int qbase = b * NQ + t0 * LL + qg * 32;
  const ushort* qp0 = qkv + (size_t)(qbase + l15) * 1536 + h * HD + kg * 8;
  const ushort* qp1 = qkv + (size_t)(qbase + 16 + l15) * 1536 + h * HD + kg * 8;
  bf16x8 qa0 = *(const bf16x8*)qp0;
  bf16x8 qa1 = *(const bf16x8*)(qp0 + 32);
  bf16x8 qb0 = *(const bf16x8*)qp1;
  bf16x8 qb1 = *(const bf16x8*)(qp1 + 32);

  f32x4 acc[2][4];
#pragma unroll
  for (int qf = 0; qf < 2; ++qf)
#pragma unroll
    for (int d = 0; d < 4; ++d) acc[qf][d] = (f32x4){0, 0, 0, 0};
  float Lacc[2] = {0.f, 0.f};
  ushort* Pt = (ushort*)smem + wv * 2304;  // 2 strips of 1152 (single-buffered)

  int kts[4]; int nkt = 0;
#pragma unroll
  for (int ki = 0; ki < 4; ++ki) {
    int kt = ks * 4 + ki;
    if (ctx_mask[b * TT + kt] != 0 && kt != t0 + 4) kts[nkt++] = kt;
  }

  const ushort* vctxb = vctxT + (size_t)h * HD * (BB * NCTX) + b * NCTX;
  for (int ki = 0; ki < nkt; ++ki) {
    int kt = kts[ki];
    attn_tile32(kctx + (size_t)(b * NCTX + kt * LL) * CC + h * HD, CC,
                vctxb + kt * LL, BB * NCTX,
                qa0, qa1, qb0, qb1, l15, kg, Pt, acc, Lacc);
  }
  if (ks == 0) {
    attn_tile32(qkv + (size_t)(b * NQ + t0 * LL) * 1536 + CC + h * HD, 1536,
                vselfT + (size_t)h * HD * (BB * NQ) + b * NQ + t0 * LL, BB * NQ,
                qa0, qa1, qb0, qb1, l15, kg, Pt, acc, Lacc);
  }

  float L0 = Lacc[0], L1 = Lacc[1];
  L0 += __shfl_xor(L0, 16, 64); L0 += __shfl_xor(L0, 32, 64);
  L1 += __shfl_xor(L1, 16, 64); L1 += __shfl_xor(L1, 32, 64);

  // ---- merge: ks1..3 publish (plain sums), ks0 adds & writes ----
  __syncthreads();
  if (ks) {
    float* reg = smem + (size_t)(qg * 3 + ks - 1) * 2176;  // 2048 acc + 128 L
#pragma unroll
    for (int qf = 0; qf < 2; ++qf)
#pragma unroll
      for (int d = 0; d < 4; ++d)
        *(f32x4*)(reg + (qf * 64 + lane) * 16 + d * 4) = acc[qf][d];
    reg[2048 + lane * 2]     = L0;
    reg[2048 + lane * 2 + 1] = L1;
  }
  __syncthreads();
  if (!ks) {
    float Ls[2] = {L0, L1};
    f32x4 o[2][4];
#pragma unroll
    for (int qf = 0; qf < 2; ++qf)
#pragma unroll
      for (int d = 0; d < 4; ++d) o[qf][d] = acc[qf][d];
#pragma unroll
    for (int j = 0; j < 3; ++j) {
      const float* reg = smem + (size_t)(qg * 3 + j) * 2176;
      Ls[0] += reg[2048 + lane * 2];
      Ls[1] += reg[2048 + lane * 2 + 1];
#pragma unroll
      for (int qf = 0; qf < 2; ++qf)
#pragma unroll
        for (int d = 0; d < 4; ++d)
          o[qf][d] += *(const f32x4*)(reg + (qf * 64 + lane) * 16 + d * 4);
    }
#pragma unroll
    for (int qf = 0; qf < 2; ++qf) {
      float inv = 1.f / Ls[qf];
      int orow = qbase + qf * 16 + l15;
#pragma unroll
      for (int d = 0; d < 4; ++d) {
        ushort4 ov = { f2bf(o[qf][d][0] * inv), f2bf(o[qf][d][1] * inv),
                       f2bf(o[qf][d][2] * inv), f2bf(o[qf][d][3] * inv) };
        *(ushort4*)(aout + (size_t)orow * CC + h * HD + d * 16 + kg * 4) = ov;
      }
    }
  }
}

extern "C" void kernel_launch(void* const* d_in, const int* in_sizes, int n_in,
                              void* d_out, int out_size, void* d_ws, size_t ws_size,
                              hipStream_t stream) {
  const float* x        = (const float*)d_in[0];
  const float* x_ctx    = (const float*)d_in[1];
  const float* dx_ctx   = (const float*)d_in[2];
  const int*   ctx_mask = (const int*)d_in[3];
  const float* qkv_w    = (const float*)d_in[4];
  const float* k_w      = (const float*)d_in[5];
  const float* v_w      = (const float*)d_in[6];
  const float* proj_w   = (const float*)d_in[7];
  const float* proj_b   = (const float*)d_in[8];
  float* out = (float*)d_out;

  ushort* ws = (ushort*)d_ws;   // element offsets (bf16)
  ushort* qkvwb  = ws;                    //  786432
  ushort* kwb    = ws + 786432;           //  262144
  ushort* vwb    = ws + 1048576;          //  262144
  ushort* pwb    = ws + 1310720;          //  262144
  ushort* xb     = ws + 1572864;          // 1572864  (3072x512)
  ushort* xcb    = ws + 3145728;          // 2097152  (4096x512)
  ushort* dxb    = ws + 5242880;          // 2097152  (4096x512)
  ushort* qkv    = ws + 7340032;          // 3072x1536
  ushort* kctx   = ws + 12058624;         // 4096x512
  ushort* vctxT  = ws + 14155776;         // 512x4096
  ushort* vselfT = ws + 16252928;         // 512x3072
  ushort* aout   = ws + 17825792;         // 3072x512  (end 19398656 el = 38.8MB)

  cvt_all<<<7168, 256, 0, stream>>>(qkv_w, k_w, v_w, proj_w, x, x_ctx, dx_ctx, ws);
  gemm3<<<544, 256, 0, stream>>>(xb, dxb, xcb, qkvwb, kwb, vwb,
                                 qkv, vselfT, kctx, vctxT);
  flash_attn<<<384, 512, 0, stream>>>(qkv, kctx, vctxT, vselfT, ctx_mask, aout);
  gemm_proj<<<192, 256, 0, stream>>>(aout, pwb, proj_b, out);
}